// Round 4
// baseline (448.391 us; speedup 1.0000x reference)
//
#include <hip/hip_runtime.h>
#include <math.h>

#define IN_DIM 256
#define HID 64
#define NC 32
#define NEG 0.01f
#define INF_NEG -1e30f
#define SX 36       // X tile stride (words), BK=32: 16B rows + 4-word pad rotates banks
#define SX2 68      // gemm2 full-K tile stride (words): 64 + 4 pad
#define MAXNBK 512  // max buckets (N <= 131072 for 17-bit dst packing)
#define SLOT 8256   // per-bucket tmp capacity; 33KB stride breaks L2 set aliasing
#define BCAP 12288  // bucket scatter LDS capacity (entries)
#define BIN_CHUNK 8192

static inline int ceil_div(int a, int b){ return (a + b - 1) / b; }

static __device__ __forceinline__ float lrelu(float x){ return x > 0.f ? x : NEG * x; }

// ---------------- CSR build ----------------

// Phase A: bucket edges by src>>8 into fixed slots tmp[b*SLOT ...], entry = (src&255)<<17 | dst.
// LDS-reorders each 8192-edge chunk bucket-contiguously so global writes are coalesced runs.
__global__ __launch_bounds__(256) void bin_kernel(const int* __restrict__ src,
      const int* __restrict__ dst, int* __restrict__ cursor,
      unsigned int* __restrict__ tmp, int E, int nbk){
  __shared__ unsigned int payload[BIN_CHUNK];
  __shared__ unsigned short bid[BIN_CHUNK];
  __shared__ int cnt[MAXNBK];
  __shared__ int lofs[MAXNBK];
  __shared__ int gbase[MAXNBK];
  __shared__ int s2[256];
  int tid = threadIdx.x;
  int beg = blockIdx.x * BIN_CHUNK;
  int end = min(E, beg + BIN_CHUNK);
  int len = end - beg;

  for (int i = tid; i < MAXNBK; i += 256) cnt[i] = 0;
  __syncthreads();
  for (int e = beg + tid; e < end; e += 256)
    atomicAdd(&cnt[src[e] >> 8], 1);
  __syncthreads();
  // exclusive scan of cnt[0..511] (2 elems/thread)
  int a0 = cnt[2 * tid], a1 = cnt[2 * tid + 1];
  int pair = a0 + a1;
  s2[tid] = pair; __syncthreads();
  int val = pair;
  for (int off = 1; off < 256; off <<= 1){
    int add = (tid >= off) ? s2[tid - off] : 0;
    __syncthreads();
    val += add; s2[tid] = val;
    __syncthreads();
  }
  int ep = val - pair;
  lofs[2 * tid] = ep;
  lofs[2 * tid + 1] = ep + a0;
  __syncthreads();
  // reserve global runs, reset cnt as rank counters
  for (int i = tid; i < nbk; i += 256){
    int c = cnt[i];
    gbase[i] = (c > 0) ? atomicAdd(&cursor[i], c) : 0;
  }
  __syncthreads();
  for (int i = tid; i < MAXNBK; i += 256) cnt[i] = 0;
  __syncthreads();
  // reorder into LDS bucket-contiguously
  for (int e = beg + tid; e < end; e += 256){
    int s = src[e];
    int b = s >> 8;
    int r = atomicAdd(&cnt[b], 1);
    int pos = lofs[b] + r;
    payload[pos] = ((unsigned)(s & 255) << 17) | (unsigned)dst[e];
    bid[pos] = (unsigned short)b;
  }
  __syncthreads();
  // coalesced run writes
  for (int pos = tid; pos < len; pos += 256){
    int b = bid[pos];
    int idx = pos - lofs[b];
    int g = gbase[b] + idx;
    if (g < SLOT) tmp[(size_t)b * SLOT + g] = payload[pos];
  }
}

// Phase B: exclusive scan of bucket counts -> bucket segment bases. One block.
__global__ __launch_bounds__(512) void bucket_base_kernel(const int* __restrict__ cursor,
      int* __restrict__ bbase, int nbk){
  __shared__ int sh[512];
  int tid = threadIdx.x;
  int v = (tid < nbk) ? min(cursor[tid], SLOT) : 0;
  sh[tid] = v; __syncthreads();
  int val = v;
  for (int off = 1; off < 512; off <<= 1){
    int add = (tid >= off) ? sh[tid - off] : 0;
    __syncthreads();
    val += add; sh[tid] = val;
    __syncthreads();
  }
  if (tid < nbk) bbase[tid] = val - v;
}

// Phase C: one block per bucket; derive row_ptr, scatter to exact positions in LDS,
// write csr coalesced.
__global__ __launch_bounds__(256) void bucket_scatter_kernel(const unsigned int* __restrict__ tmp,
      const int* __restrict__ cursor, const int* __restrict__ bbase,
      int* __restrict__ row_ptr, int* __restrict__ csr, int n){
  __shared__ int cnt[256];
  __shared__ int cur[256];
  __shared__ int lbuf[BCAP];
  int tid = threadIdx.x;
  int b = blockIdx.x;
  int n0 = b << 8;
  int nn = min(256, n - n0);
  int len = min(cursor[b], SLOT);
  int segb = bbase[b];
  const unsigned int* T = tmp + (size_t)b * SLOT;
  cnt[tid] = 0;
  __syncthreads();
  for (int e = tid; e < len; e += 256) atomicAdd(&cnt[T[e] >> 17], 1);
  __syncthreads();
  int tv = cnt[tid];
  int val = tv;
  for (int off = 1; off < 256; off <<= 1){
    int add = (tid >= off) ? cnt[tid - off] : 0;
    __syncthreads();
    val += add; cnt[tid] = val;
    __syncthreads();
  }
  int excl = val - tv;
  cur[tid] = excl;
  if (tid < nn) row_ptr[n0 + tid] = segb + excl;
  if (n0 + nn == n && tid == 0) row_ptr[n] = segb + len;
  __syncthreads();
  if (len <= BCAP){
    for (int e = tid; e < len; e += 256){
      unsigned v = T[e];
      int pos = atomicAdd(&cur[v >> 17], 1);
      lbuf[pos] = (int)(v & 0x1FFFF);
    }
    __syncthreads();
    for (int e = tid; e < len; e += 256) csr[segb + e] = lbuf[e];
  } else {
    for (int e = tid; e < len; e += 256){
      unsigned v = T[e];
      int pos = atomicAdd(&cur[v >> 17], 1);
      csr[segb + pos] = (int)(v & 0x1FFFF);
    }
  }
}

// ---- fallback CSR path (N > 2^17 only; never hit at this problem size) ----

__global__ void hist_kernel(const int* __restrict__ src, int* __restrict__ counts, int E){
  int i = blockIdx.x * blockDim.x + threadIdx.x;
  if (i < E) atomicAdd(&counts[src[i]], 1);
}
__global__ void scan_blocks_kernel(const int* __restrict__ counts, int* __restrict__ excl,
                                   int* __restrict__ bsums, int n){
  __shared__ int sh[256];
  int tid = threadIdx.x;
  int base = blockIdx.x * 1024 + tid * 4;
  int c[4]; int tsum = 0;
  #pragma unroll
  for (int j = 0; j < 4; j++){ int i = base + j; c[j] = (i < n) ? counts[i] : 0; tsum += c[j]; }
  sh[tid] = tsum; __syncthreads();
  int val = tsum;
  for (int off = 1; off < 256; off <<= 1){
    int add = (tid >= off) ? sh[tid - off] : 0;
    __syncthreads();
    val += add; sh[tid] = val;
    __syncthreads();
  }
  int p = val - tsum;
  #pragma unroll
  for (int j = 0; j < 4; j++){ int i = base + j; if (i < n) excl[i] = p; p += c[j]; }
  if (tid == 255) bsums[blockIdx.x] = val;
}
__global__ void scan_sums_kernel(int* __restrict__ bsums, int* __restrict__ row_ptr,
                                 int nb, int n, int E){
  __shared__ int sh[256];
  int tid = threadIdx.x;
  int v = (tid < nb) ? bsums[tid] : 0;
  sh[tid] = v; __syncthreads();
  int val = v;
  for (int off = 1; off < 256; off <<= 1){
    int add = (tid >= off) ? sh[tid - off] : 0;
    __syncthreads();
    val += add; sh[tid] = val;
    __syncthreads();
  }
  if (tid < nb) bsums[tid] = val - v;
  if (tid == 0) row_ptr[n] = E;
}
__global__ void add_offsets_kernel(int* __restrict__ excl, const int* __restrict__ bsums, int n){
  int i = blockIdx.x * 1024 + threadIdx.x;
  if (i < n) excl[i] += bsums[blockIdx.x];
}
__global__ void scatter_kernel(const int* __restrict__ src, const int* __restrict__ dst,
                               const int* __restrict__ row_ptr, int* __restrict__ fill,
                               int* __restrict__ csr, int E){
  int i = blockIdx.x * blockDim.x + threadIdx.x;
  if (i >= E) return;
  int s = src[i];
  int pos = row_ptr[s] + atomicAdd(&fill[s], 1);
  csr[pos] = dst[i];
}

// ---------------- GEMM 1: X[N,256] @ W1[256,64] -> H, s, d ----------------
// BM=64, 4x4 tile, BK=32, grid 1563 (all resident). DS-pipe relief: only xs
// lives in LDS (4 ds_read_b128/kq instead of 8); W streams from global (L2-
// resident, 256B unique/wave-instr) through a 1-kq-ahead register double
// buffer (wa/wb) so the ~200cy L2 latency hides under the previous kq's FMAs.

__global__ __launch_bounds__(256) void gemm1_kernel(const float* __restrict__ X, const float* __restrict__ W,
      const float* __restrict__ a, float* __restrict__ H,
      float* __restrict__ svec, float* __restrict__ dvec, int n){
  __shared__ float xs[64 * SX];   // 9216 B
  int tid = threadIdx.x;
  int r0 = blockIdx.x * 64;
  int tr = tid >> 4;              // 16 row-groups x 4 rows
  int tc = tid & 15;              // 16 col-groups x 4 cols
  int srow = tid >> 3, sc8 = tid & 7;   // staging: 32 rows/pass x 8 float4 chunks
  int gr0 = r0 + srow, gr1 = r0 + 32 + srow;
  const float* xp0 = X + (size_t)gr0 * IN_DIM + sc8 * 4;
  const float* xp1 = X + (size_t)gr1 * IN_DIM + sc8 * 4;
  bool v0 = gr0 < n, v1 = gr1 < n;
  float4 zero = make_float4(0.f, 0.f, 0.f, 0.f);
  float4 pf0 = v0 ? *(const float4*)xp0 : zero;
  float4 pf1 = v1 ? *(const float4*)xp1 : zero;

  const float* Wc = W + tc * 4;   // this thread's 4-column slice of W[256][64]
  float4 wa[4], wb[4];
  #pragma unroll
  for (int dk = 0; dk < 4; dk++) wa[dk] = *(const float4*)(Wc + (size_t)dk * 64);

  float acc[4][4];
  #pragma unroll
  for (int i = 0; i < 4; i++)
    #pragma unroll
    for (int j = 0; j < 4; j++) acc[i][j] = 0.f;

  for (int kb = 0; kb < 8; kb++){
    __syncthreads();
    *(float4*)(xs + srow * SX + sc8 * 4) = pf0;
    *(float4*)(xs + (32 + srow) * SX + sc8 * 4) = pf1;
    __syncthreads();
    if (kb < 7){
      pf0 = v0 ? *(const float4*)(xp0 + (kb + 1) * 32) : zero;
      pf1 = v1 ? *(const float4*)(xp1 + (kb + 1) * 32) : zero;
    }
    #pragma unroll
    for (int kq = 0; kq < 8; kq++){
      float4* wcur = (kq & 1) ? wb : wa;   // compile-time after unroll
      float4* wnxt = (kq & 1) ? wa : wb;
      // issue next-kq W loads first (kq==7 fetches next kb's kq0)
      if (kq < 7 || kb < 7){
        const float* Wn = Wc + (size_t)(kb * 32 + (kq + 1) * 4) * 64;
        #pragma unroll
        for (int dk = 0; dk < 4; dk++) wnxt[dk] = *(const float4*)(Wn + (size_t)dk * 64);
      }
      float xr[4][4];
      #pragma unroll
      for (int i = 0; i < 4; i++){
        float4 v = *(const float4*)(xs + (tr * 4 + i) * SX + kq * 4);
        xr[i][0] = v.x; xr[i][1] = v.y; xr[i][2] = v.z; xr[i][3] = v.w;
      }
      #pragma unroll
      for (int dk = 0; dk < 4; dk++){
        #pragma unroll
        for (int i = 0; i < 4; i++){
          acc[i][0] = fmaf(xr[i][dk], wcur[dk].x, acc[i][0]);
          acc[i][1] = fmaf(xr[i][dk], wcur[dk].y, acc[i][1]);
          acc[i][2] = fmaf(xr[i][dk], wcur[dk].z, acc[i][2]);
          acc[i][3] = fmaf(xr[i][dk], wcur[dk].w, acc[i][3]);
        }
      }
    }
  }

  float av[4], bv[4];
  #pragma unroll
  for (int j = 0; j < 4; j++){ av[j] = a[tc * 4 + j]; bv[j] = a[64 + tc * 4 + j]; }
  float sp[4], dp[4];
  #pragma unroll
  for (int i = 0; i < 4; i++){
    float s = 0.f, d = 0.f;
    #pragma unroll
    for (int j = 0; j < 4; j++){ s = fmaf(acc[i][j], av[j], s); d = fmaf(acc[i][j], bv[j], d); }
    sp[i] = s; dp[i] = d;
  }
  #pragma unroll
  for (int off = 1; off < 16; off <<= 1){
    #pragma unroll
    for (int i = 0; i < 4; i++){
      sp[i] += __shfl_xor(sp[i], off, 16);
      dp[i] += __shfl_xor(dp[i], off, 16);
    }
  }
  #pragma unroll
  for (int i = 0; i < 4; i++){
    int r = r0 + tr * 4 + i;
    if (r < n){
      *(float4*)(H + (size_t)r * 64 + tc * 4) = make_float4(acc[i][0], acc[i][1], acc[i][2], acc[i][3]);
      if (tc == 0){ svec[r] = sp[i]; dvec[r] = dp[i]; }
    }
  }
}

// ---------------- GEMM 2: hid[N,64] @ W2[64,32] -> H2, s, d ----------------
// BM=64, thread owns 4x2. K=64 fits entirely: stage X-slab + W2 once, ONE
// barrier total, then barrier-free compute. LDS 25.6KB -> 6 blocks/CU.

__global__ __launch_bounds__(256) void gemm2_kernel(const float* __restrict__ X, const float* __restrict__ W,
      const float* __restrict__ a, float* __restrict__ H,
      float* __restrict__ svec, float* __restrict__ dvec, int n){
  __shared__ float xs[64 * SX2];  // 17408 B
  __shared__ float ws[64 * 32];   // 8192 B
  int tid = threadIdx.x;
  int r0 = blockIdx.x * 64;
  int tr = tid >> 4;
  int tc = tid & 15;

  #pragma unroll
  for (int p = 0; p < 4; p++){
    int lin = p * 256 + tid;       // 0..1023
    int row = lin >> 4;            // 0..63
    int c4 = lin & 15;             // 0..15
    int gr = r0 + row;
    float4 v = make_float4(0.f, 0.f, 0.f, 0.f);
    if (gr < n) v = *(const float4*)(X + (size_t)gr * HID + c4 * 4);
    *(float4*)(xs + row * SX2 + c4 * 4) = v;
  }
  #pragma unroll
  for (int p = 0; p < 2; p++){
    int lin = p * 256 + tid;       // 0..511
    int k = lin >> 3, c4 = lin & 7;
    *(float4*)(ws + k * 32 + c4 * 4) = *(const float4*)(W + (size_t)k * 32 + c4 * 4);
  }
  __syncthreads();

  float acc[4][2];
  #pragma unroll
  for (int i = 0; i < 4; i++){ acc[i][0] = 0.f; acc[i][1] = 0.f; }

  #pragma unroll
  for (int kq = 0; kq < 16; kq++){
    float xr[4][4];
    #pragma unroll
    for (int i = 0; i < 4; i++){
      float4 v = *(const float4*)(xs + (tr * 4 + i) * SX2 + kq * 4);
      xr[i][0] = v.x; xr[i][1] = v.y; xr[i][2] = v.z; xr[i][3] = v.w;
    }
    #pragma unroll
    for (int dk = 0; dk < 4; dk++){
      float2 w2 = *(const float2*)(ws + (size_t)(kq * 4 + dk) * 32 + tc * 2);
      #pragma unroll
      for (int i = 0; i < 4; i++){
        acc[i][0] = fmaf(xr[i][dk], w2.x, acc[i][0]);
        acc[i][1] = fmaf(xr[i][dk], w2.y, acc[i][1]);
      }
    }
  }

  float a0 = a[tc * 2], a1 = a[tc * 2 + 1];
  float b0 = a[32 + tc * 2], b1 = a[32 + tc * 2 + 1];
  float sp[4], dp[4];
  #pragma unroll
  for (int i = 0; i < 4; i++){
    sp[i] = fmaf(acc[i][0], a0, acc[i][1] * a1);
    dp[i] = fmaf(acc[i][0], b0, acc[i][1] * b1);
  }
  #pragma unroll
  for (int off = 1; off < 16; off <<= 1){
    #pragma unroll
    for (int i = 0; i < 4; i++){
      sp[i] += __shfl_xor(sp[i], off, 16);
      dp[i] += __shfl_xor(dp[i], off, 16);
    }
  }
  #pragma unroll
  for (int i = 0; i < 4; i++){
    int r = r0 + tr * 4 + i;
    if (r < n){
      *(float2*)(H + (size_t)r * NC + tc * 2) = make_float2(acc[i][0], acc[i][1]);
      if (tc == 0){ svec[r] = sp[i]; dvec[r] = dp[i]; }
    }
  }
}

// ---------------- Aggregate layer 1: chunked two-phase softmax + ELU, D=64, 16 lanes/node ----------------

__global__ __launch_bounds__(256) void agg1_kernel(const float* __restrict__ H, const float* __restrict__ sv,
      const float* __restrict__ dv, const int* __restrict__ row_ptr, const int* __restrict__ csr,
      float* __restrict__ out, int n){
  int t = blockIdx.x * 256 + threadIdx.x;
  int g = t >> 4, fl = t & 15;
  if (g >= n) return;
  int beg = row_ptr[g], end = row_ptr[g + 1];
  float si = sv[g];
  float m = INF_NEG, l = 0.f;
  float ox = 0.f, oy = 0.f, oz = 0.f, ow = 0.f;

  for (int cb = beg; cb < end; cb += 32){
    int ce = min(cb + 32, end);
    int e0 = cb + fl, e1 = cb + 16 + fl;
    int d0 = 0, d1 = 0;
    float ev0 = INF_NEG, ev1 = INF_NEG;
    if (e0 < ce){ d0 = csr[e0]; ev0 = lrelu(si + dv[d0]); }
    if (e1 < ce){ d1 = csr[e1]; ev1 = lrelu(si + dv[d1]); }
    float lm = fmaxf(ev0, ev1);
    #pragma unroll
    for (int off = 1; off < 16; off <<= 1) lm = fmaxf(lm, __shfl_xor(lm, off, 16));
    float nm = fmaxf(m, lm);
    float alpha = __expf(m - nm);
    m = nm;
    ev0 = __expf(ev0 - nm);
    ev1 = __expf(ev1 - nm);
    float ll = ev0 + ev1;
    #pragma unroll
    for (int off = 1; off < 16; off <<= 1) ll += __shfl_xor(ll, off, 16);
    l = l * alpha + ll;
    ox *= alpha; oy *= alpha; oz *= alpha; ow *= alpha;
    #pragma unroll
    for (int jj = 0; jj < 16; jj++){
      int e = cb + jj;
      if (e >= ce) break;
      float wgt = __shfl(ev0, jj, 16);
      int dd = __shfl(d0, jj, 16);
      float4 v = *(const float4*)(H + (size_t)dd * 64 + fl * 4);
      ox = fmaf(wgt, v.x, ox); oy = fmaf(wgt, v.y, oy);
      oz = fmaf(wgt, v.z, oz); ow = fmaf(wgt, v.w, ow);
    }
    #pragma unroll
    for (int jj = 0; jj < 16; jj++){
      int e = cb + 16 + jj;
      if (e >= ce) break;
      float wgt = __shfl(ev1, jj, 16);
      int dd = __shfl(d1, jj, 16);
      float4 v = *(const float4*)(H + (size_t)dd * 64 + fl * 4);
      ox = fmaf(wgt, v.x, ox); oy = fmaf(wgt, v.y, oy);
      oz = fmaf(wgt, v.z, oz); ow = fmaf(wgt, v.w, ow);
    }
  }
  float inv = (l > 0.f) ? 1.f / l : 0.f;
  ox *= inv; oy *= inv; oz *= inv; ow *= inv;
  ox = ox > 0.f ? ox : __expf(ox) - 1.f;
  oy = oy > 0.f ? oy : __expf(oy) - 1.f;
  oz = oz > 0.f ? oz : __expf(oz) - 1.f;
  ow = ow > 0.f ? ow : __expf(ow) - 1.f;
  *(float4*)(out + (size_t)g * 64 + fl * 4) = make_float4(ox, oy, oz, ow);
}

// ---------------- Aggregate layer 2: chunked two-phase softmax + log_softmax, D=32, 8 lanes/node ----------------

__global__ __launch_bounds__(256) void agg2_kernel(const float* __restrict__ H, const float* __restrict__ sv,
      const float* __restrict__ dv, const int* __restrict__ row_ptr, const int* __restrict__ csr,
      float* __restrict__ out, int n){
  int t = blockIdx.x * 256 + threadIdx.x;
  int g = t >> 3, fl = t & 7;
  if (g >= n) return;
  int beg = row_ptr[g], end = row_ptr[g + 1];
  float si = sv[g];
  float m = INF_NEG, l = 0.f;
  float ox = 0.f, oy = 0.f, oz = 0.f, ow = 0.f;

  for (int cb = beg; cb < end; cb += 32){
    int ce = min(cb + 32, end);
    float ev[4]; int dd4[4];
    float lm = INF_NEG;
    #pragma unroll
    for (int s = 0; s < 4; s++){
      int e = cb + s * 8 + fl;
      ev[s] = INF_NEG; dd4[s] = 0;
      if (e < ce){ dd4[s] = csr[e]; ev[s] = lrelu(si + dv[dd4[s]]); }
      lm = fmaxf(lm, ev[s]);
    }
    #pragma unroll
    for (int off = 1; off < 8; off <<= 1) lm = fmaxf(lm, __shfl_xor(lm, off, 8));
    float nm = fmaxf(m, lm);
    float alpha = __expf(m - nm);
    m = nm;
    float ll = 0.f;
    #pragma unroll
    for (int s = 0; s < 4; s++){ ev[s] = __expf(ev[s] - nm); ll += ev[s]; }
    #pragma unroll
    for (int off = 1; off < 8; off <<= 1) ll += __shfl_xor(ll, off, 8);
    l = l * alpha + ll;
    ox *= alpha; oy *= alpha; oz *= alpha; ow *= alpha;
    #pragma unroll
    for (int s = 0; s < 4; s++){
      #pragma unroll
      for (int jj = 0; jj < 8; jj++){
        int e = cb + s * 8 + jj;
        if (e >= ce) break;
        float wgt = __shfl(ev[s], jj, 8);
        int dd = __shfl(dd4[s], jj, 8);
        float4 v = *(const float4*)(H + (size_t)dd * 32 + fl * 4);
        ox = fmaf(wgt, v.x, ox); oy = fmaf(wgt, v.y, oy);
        oz = fmaf(wgt, v.z, oz); ow = fmaf(wgt, v.w, ow);
      }
    }
  }
  float inv = (l > 0.f) ? 1.f / l : 0.f;
  ox *= inv; oy *= inv; oz *= inv; ow *= inv;
  float tm = fmaxf(fmaxf(ox, oy), fmaxf(oz, ow));
  #pragma unroll
  for (int off = 1; off < 8; off <<= 1) tm = fmaxf(tm, __shfl_xor(tm, off, 8));
  float se = __expf(ox - tm) + __expf(oy - tm) + __expf(oz - tm) + __expf(ow - tm);
  #pragma unroll
  for (int off = 1; off < 8; off <<= 1) se += __shfl_xor(se, off, 8);
  float lg = tm + __logf(se);
  *(float4*)(out + (size_t)g * 32 + fl * 4) = make_float4(ox - lg, oy - lg, oz - lg, ow - lg);
}

// ---------------- launch ----------------

extern "C" void kernel_launch(void* const* d_in, const int* in_sizes, int n_in,
                              void* d_out, int out_size, void* d_ws, size_t ws_size,
                              hipStream_t stream) {
  (void)n_in; (void)out_size; (void)ws_size;
  const float* X  = (const float*)d_in[0];
  const int*   EI = (const int*)d_in[1];
  const float* W1 = (const float*)d_in[2];
  const float* W2 = (const float*)d_in[3];
  const float* A1 = (const float*)d_in[4];
  const float* A2 = (const float*)d_in[5];
  float* out = (float*)d_out;

  int N = in_sizes[0] / IN_DIM;
  int E = in_sizes[1] / 2;
  const int* src = EI;
  const int* dst = EI + E;

  auto align_up = [](size_t x){ return (x + 511) & ~(size_t)511; };
  char* w = (char*)d_ws;
  int* counts  = (int*)w;   w += align_up((size_t)N * 4);          // fallback fill only
  int* cursor  = (int*)w;   w += align_up((size_t)MAXNBK * 4);
  int* bbase   = (int*)w;   w += align_up((size_t)MAXNBK * 4);
  int* row_ptr = (int*)w;   w += align_up((size_t)(N + 1) * 4);
  int* bsums   = (int*)w;   w += align_up(1024);
  int* csr     = (int*)w;   w += align_up((size_t)E * 4);
  float* H1    = (float*)w; w += align_up((size_t)N * 64 * 4);
  float* hid   = (float*)w; w += align_up((size_t)N * 64 * 4);
  float* s1    = (float*)w; w += align_up((size_t)N * 4);
  float* d1    = (float*)w; w += align_up((size_t)N * 4);
  float* s2    = (float*)w; w += align_up((size_t)N * 4);
  float* d2    = (float*)w; w += align_up((size_t)N * 4);
  float* H2    = H1;                       // H1 dead after agg1; reuse
  unsigned int* tmp = (unsigned int*)hid;  // hid dead until agg1; nbk*SLOT*4 <= N*64*4

  int nbk = ceil_div(N, 256);

  if (N <= (1 << 17) && nbk <= MAXNBK && (size_t)nbk * SLOT <= (size_t)N * 64){
    hipMemsetAsync(cursor, 0, (size_t)nbk * 4, stream);
    bin_kernel<<<ceil_div(E, BIN_CHUNK), 256, 0, stream>>>(src, dst, cursor, tmp, E, nbk);
    bucket_base_kernel<<<1, 512, 0, stream>>>(cursor, bbase, nbk);
    bucket_scatter_kernel<<<nbk, 256, 0, stream>>>(tmp, cursor, bbase, row_ptr, csr, N);
  } else {
    int nb = ceil_div(N, 1024);
    hipMemsetAsync(counts, 0, (size_t)N * 4, stream);
    hist_kernel<<<ceil_div(E, 256), 256, 0, stream>>>(src, counts, E);
    scan_blocks_kernel<<<nb, 256, 0, stream>>>(counts, row_ptr, bsums, N);
    scan_sums_kernel<<<1, 256, 0, stream>>>(bsums, row_ptr, nb, N, E);
    add_offsets_kernel<<<nb, 1024, 0, stream>>>(row_ptr, bsums, N);
    hipMemsetAsync(counts, 0, (size_t)N * 4, stream);
    scatter_kernel<<<ceil_div(E, 256), 256, 0, stream>>>(src, dst, row_ptr, counts, csr, E);
  }

  gemm1_kernel<<<ceil_div(N, 64), 256, 0, stream>>>(X, W1, A1, H1, s1, d1, N);
  agg1_kernel<<<ceil_div(N * 16, 256), 256, 0, stream>>>(H1, s1, d1, row_ptr, csr, hid, N);
  gemm2_kernel<<<ceil_div(N, 64), 256, 0, stream>>>(hid, W2, A2, H2, s2, d2, N);
  agg2_kernel<<<ceil_div(N * 8, 256), 256, 0, stream>>>(H2, s2, d2, row_ptr, csr, out, N);
}

// Round 5
// 369.666 us; speedup vs baseline: 1.2130x; 1.2130x over previous
//
#include <hip/hip_runtime.h>
#include <math.h>

#define IN_DIM 256
#define HID 64
#define NC 32
#define NEG 0.01f
#define INF_NEG -1e30f
#define SX 36       // X tile stride (words), BK=32: 16B rows + 4-word pad rotates banks
#define SX2 68      // gemm2 full-K tile stride (words): 64 + 4 pad
#define MAXNBK 512  // max buckets (N <= 131072 for 17-bit dst packing)
#define SLOT 8256   // per-bucket tmp capacity; 33KB stride breaks L2 set aliasing
#define BCAP 12288  // bucket scatter LDS capacity (entries)
#define BIN_CHUNK 4096  // 391 blocks (1.5/CU) + 31KB LDS (5 blocks/CU) vs 8192's 196 blocks/55KB

static inline int ceil_div(int a, int b){ return (a + b - 1) / b; }

static __device__ __forceinline__ float lrelu(float x){ return x > 0.f ? x : NEG * x; }

// ---------------- CSR build ----------------

// Phase A: bucket edges by src>>8 into fixed slots tmp[b*SLOT ...], entry = (src&255)<<17 | dst.
// LDS-reorders each chunk bucket-contiguously so global writes are coalesced runs.
__global__ __launch_bounds__(256) void bin_kernel(const int* __restrict__ src,
      const int* __restrict__ dst, int* __restrict__ cursor,
      unsigned int* __restrict__ tmp, int E, int nbk){
  __shared__ unsigned int payload[BIN_CHUNK];
  __shared__ unsigned short bid[BIN_CHUNK];
  __shared__ int cnt[MAXNBK];
  __shared__ int lofs[MAXNBK];
  __shared__ int gbase[MAXNBK];
  __shared__ int s2[256];
  int tid = threadIdx.x;
  int beg = blockIdx.x * BIN_CHUNK;
  int end = min(E, beg + BIN_CHUNK);
  int len = end - beg;

  for (int i = tid; i < MAXNBK; i += 256) cnt[i] = 0;
  __syncthreads();
  for (int e = beg + tid; e < end; e += 256)
    atomicAdd(&cnt[src[e] >> 8], 1);
  __syncthreads();
  // exclusive scan of cnt[0..511] (2 elems/thread)
  int a0 = cnt[2 * tid], a1 = cnt[2 * tid + 1];
  int pair = a0 + a1;
  s2[tid] = pair; __syncthreads();
  int val = pair;
  for (int off = 1; off < 256; off <<= 1){
    int add = (tid >= off) ? s2[tid - off] : 0;
    __syncthreads();
    val += add; s2[tid] = val;
    __syncthreads();
  }
  int ep = val - pair;
  lofs[2 * tid] = ep;
  lofs[2 * tid + 1] = ep + a0;
  __syncthreads();
  // reserve global runs, reset cnt as rank counters
  for (int i = tid; i < nbk; i += 256){
    int c = cnt[i];
    gbase[i] = (c > 0) ? atomicAdd(&cursor[i], c) : 0;
  }
  __syncthreads();
  for (int i = tid; i < MAXNBK; i += 256) cnt[i] = 0;
  __syncthreads();
  // reorder into LDS bucket-contiguously
  for (int e = beg + tid; e < end; e += 256){
    int s = src[e];
    int b = s >> 8;
    int r = atomicAdd(&cnt[b], 1);
    int pos = lofs[b] + r;
    payload[pos] = ((unsigned)(s & 255) << 17) | (unsigned)dst[e];
    bid[pos] = (unsigned short)b;
  }
  __syncthreads();
  // coalesced run writes
  for (int pos = tid; pos < len; pos += 256){
    int b = bid[pos];
    int idx = pos - lofs[b];
    int g = gbase[b] + idx;
    if (g < SLOT) tmp[(size_t)b * SLOT + g] = payload[pos];
  }
}

// Phase B: exclusive scan of bucket counts -> bucket segment bases. One block.
__global__ __launch_bounds__(512) void bucket_base_kernel(const int* __restrict__ cursor,
      int* __restrict__ bbase, int nbk){
  __shared__ int sh[512];
  int tid = threadIdx.x;
  int v = (tid < nbk) ? min(cursor[tid], SLOT) : 0;
  sh[tid] = v; __syncthreads();
  int val = v;
  for (int off = 1; off < 512; off <<= 1){
    int add = (tid >= off) ? sh[tid - off] : 0;
    __syncthreads();
    val += add; sh[tid] = val;
    __syncthreads();
  }
  if (tid < nbk) bbase[tid] = val - v;
}

// Phase C: one block per bucket; derive row_ptr, scatter to exact positions in LDS,
// write csr coalesced.
__global__ __launch_bounds__(256) void bucket_scatter_kernel(const unsigned int* __restrict__ tmp,
      const int* __restrict__ cursor, const int* __restrict__ bbase,
      int* __restrict__ row_ptr, int* __restrict__ csr, int n){
  __shared__ int cnt[256];
  __shared__ int cur[256];
  __shared__ int lbuf[BCAP];
  int tid = threadIdx.x;
  int b = blockIdx.x;
  int n0 = b << 8;
  int nn = min(256, n - n0);
  int len = min(cursor[b], SLOT);
  int segb = bbase[b];
  const unsigned int* T = tmp + (size_t)b * SLOT;
  cnt[tid] = 0;
  __syncthreads();
  for (int e = tid; e < len; e += 256) atomicAdd(&cnt[T[e] >> 17], 1);
  __syncthreads();
  int tv = cnt[tid];
  int val = tv;
  for (int off = 1; off < 256; off <<= 1){
    int add = (tid >= off) ? cnt[tid - off] : 0;
    __syncthreads();
    val += add; cnt[tid] = val;
    __syncthreads();
  }
  int excl = val - tv;
  cur[tid] = excl;
  if (tid < nn) row_ptr[n0 + tid] = segb + excl;
  if (n0 + nn == n && tid == 0) row_ptr[n] = segb + len;
  __syncthreads();
  if (len <= BCAP){
    for (int e = tid; e < len; e += 256){
      unsigned v = T[e];
      int pos = atomicAdd(&cur[v >> 17], 1);
      lbuf[pos] = (int)(v & 0x1FFFF);
    }
    __syncthreads();
    for (int e = tid; e < len; e += 256) csr[segb + e] = lbuf[e];
  } else {
    for (int e = tid; e < len; e += 256){
      unsigned v = T[e];
      int pos = atomicAdd(&cur[v >> 17], 1);
      csr[segb + pos] = (int)(v & 0x1FFFF);
    }
  }
}

// ---- fallback CSR path (N > 2^17 only; never hit at this problem size) ----

__global__ void hist_kernel(const int* __restrict__ src, int* __restrict__ counts, int E){
  int i = blockIdx.x * blockDim.x + threadIdx.x;
  if (i < E) atomicAdd(&counts[src[i]], 1);
}
__global__ void scan_blocks_kernel(const int* __restrict__ counts, int* __restrict__ excl,
                                   int* __restrict__ bsums, int n){
  __shared__ int sh[256];
  int tid = threadIdx.x;
  int base = blockIdx.x * 1024 + tid * 4;
  int c[4]; int tsum = 0;
  #pragma unroll
  for (int j = 0; j < 4; j++){ int i = base + j; c[j] = (i < n) ? counts[i] : 0; tsum += c[j]; }
  sh[tid] = tsum; __syncthreads();
  int val = tsum;
  for (int off = 1; off < 256; off <<= 1){
    int add = (tid >= off) ? sh[tid - off] : 0;
    __syncthreads();
    val += add; sh[tid] = val;
    __syncthreads();
  }
  int p = val - tsum;
  #pragma unroll
  for (int j = 0; j < 4; j++){ int i = base + j; if (i < n) excl[i] = p; p += c[j]; }
  if (tid == 255) bsums[blockIdx.x] = val;
}
__global__ void scan_sums_kernel(int* __restrict__ bsums, int* __restrict__ row_ptr,
                                 int nb, int n, int E){
  __shared__ int sh[256];
  int tid = threadIdx.x;
  int v = (tid < nb) ? bsums[tid] : 0;
  sh[tid] = v; __syncthreads();
  int val = v;
  for (int off = 1; off < 256; off <<= 1){
    int add = (tid >= off) ? sh[tid - off] : 0;
    __syncthreads();
    val += add; sh[tid] = val;
    __syncthreads();
  }
  if (tid < nb) bsums[tid] = val - v;
  if (tid == 0) row_ptr[n] = E;
}
__global__ void add_offsets_kernel(int* __restrict__ excl, const int* __restrict__ bsums, int n){
  int i = blockIdx.x * 1024 + threadIdx.x;
  if (i < n) excl[i] += bsums[blockIdx.x];
}
__global__ void scatter_kernel(const int* __restrict__ src, const int* __restrict__ dst,
                               const int* __restrict__ row_ptr, int* __restrict__ fill,
                               int* __restrict__ csr, int E){
  int i = blockIdx.x * blockDim.x + threadIdx.x;
  if (i >= E) return;
  int s = src[i];
  int pos = row_ptr[s] + atomicAdd(&fill[s], 1);
  csr[pos] = dst[i];
}

// ---------------- GEMM 1: X[N,256] @ W1[256,64] -> H, s, d ----------------
// R2 config (measured 78us, VGPR 44): BM=64, 4x4 tile, BK=32, xs+ws in LDS,
// dual register prefetch, 2 barriers/kb, grid 1563 fully resident.

__global__ __launch_bounds__(256) void gemm1_kernel(const float* __restrict__ X, const float* __restrict__ W,
      const float* __restrict__ a, float* __restrict__ H,
      float* __restrict__ svec, float* __restrict__ dvec, int n){
  __shared__ float xs[64 * SX];   // 9216 B
  __shared__ float ws[32 * 64];   // 8192 B
  int tid = threadIdx.x;
  int r0 = blockIdx.x * 64;
  int tr = tid >> 4;              // 16 row-groups x 4 rows
  int tc = tid & 15;              // 16 col-groups x 4 cols
  int srow = tid >> 3, sc8 = tid & 7;   // staging: 32 rows/pass x 8 float4 chunks

  float4 pfx[2], pfw[2];
  #pragma unroll
  for (int p = 0; p < 2; p++){
    int row = p * 32 + srow;
    int gr = r0 + row;
    pfx[p] = make_float4(0.f, 0.f, 0.f, 0.f);
    if (gr < n) pfx[p] = *(const float4*)(X + (size_t)gr * IN_DIM + sc8 * 4);
  }
  #pragma unroll
  for (int p = 0; p < 2; p++){
    int idx = p * 256 + tid;
    int k = idx >> 4, c4 = idx & 15;
    pfw[p] = *(const float4*)(W + (size_t)k * 64 + c4 * 4);
  }

  float acc[4][4];
  #pragma unroll
  for (int i = 0; i < 4; i++)
    #pragma unroll
    for (int j = 0; j < 4; j++) acc[i][j] = 0.f;

  for (int kb = 0; kb < 8; kb++){
    __syncthreads();
    #pragma unroll
    for (int p = 0; p < 2; p++){
      int row = p * 32 + srow;
      *(float4*)(xs + row * SX + sc8 * 4) = pfx[p];
    }
    #pragma unroll
    for (int p = 0; p < 2; p++){
      int idx = p * 256 + tid;
      int k = idx >> 4, c4 = idx & 15;
      *(float4*)(ws + k * 64 + c4 * 4) = pfw[p];
    }
    if (kb < 7){
      #pragma unroll
      for (int p = 0; p < 2; p++){
        int row = p * 32 + srow;
        int gr = r0 + row;
        pfx[p] = make_float4(0.f, 0.f, 0.f, 0.f);
        if (gr < n) pfx[p] = *(const float4*)(X + (size_t)gr * IN_DIM + (kb + 1) * 32 + sc8 * 4);
      }
      #pragma unroll
      for (int p = 0; p < 2; p++){
        int idx = p * 256 + tid;
        int k = idx >> 4, c4 = idx & 15;
        pfw[p] = *(const float4*)(W + (size_t)((kb + 1) * 32 + k) * 64 + c4 * 4);
      }
    }
    __syncthreads();
    #pragma unroll
    for (int kq = 0; kq < 8; kq++){
      float xr[4][4];
      #pragma unroll
      for (int i = 0; i < 4; i++){
        float4 v = *(const float4*)(xs + (tr * 4 + i) * SX + kq * 4);
        xr[i][0] = v.x; xr[i][1] = v.y; xr[i][2] = v.z; xr[i][3] = v.w;
      }
      #pragma unroll
      for (int dk = 0; dk < 4; dk++){
        float4 w4 = *(const float4*)(ws + (size_t)(kq * 4 + dk) * 64 + tc * 4);
        float wv[4] = {w4.x, w4.y, w4.z, w4.w};
        #pragma unroll
        for (int i = 0; i < 4; i++)
          #pragma unroll
          for (int j = 0; j < 4; j++) acc[i][j] = fmaf(xr[i][dk], wv[j], acc[i][j]);
      }
    }
  }

  float av[4], bv[4];
  #pragma unroll
  for (int j = 0; j < 4; j++){ av[j] = a[tc * 4 + j]; bv[j] = a[64 + tc * 4 + j]; }
  float sp[4], dp[4];
  #pragma unroll
  for (int i = 0; i < 4; i++){
    float s = 0.f, d = 0.f;
    #pragma unroll
    for (int j = 0; j < 4; j++){ s = fmaf(acc[i][j], av[j], s); d = fmaf(acc[i][j], bv[j], d); }
    sp[i] = s; dp[i] = d;
  }
  #pragma unroll
  for (int off = 1; off < 16; off <<= 1){
    #pragma unroll
    for (int i = 0; i < 4; i++){
      sp[i] += __shfl_xor(sp[i], off, 16);
      dp[i] += __shfl_xor(dp[i], off, 16);
    }
  }
  #pragma unroll
  for (int i = 0; i < 4; i++){
    int r = r0 + tr * 4 + i;
    if (r < n){
      *(float4*)(H + (size_t)r * 64 + tc * 4) = make_float4(acc[i][0], acc[i][1], acc[i][2], acc[i][3]);
      if (tc == 0){ svec[r] = sp[i]; dvec[r] = dp[i]; }
    }
  }
}

// ---------------- GEMM 2: hid[N,64] @ W2[64,32] -> H2, s, d ----------------
// BM=64, thread owns 4x2. K=64 fits entirely: stage X-slab + W2 once, ONE
// barrier total, then barrier-free compute. LDS 25.6KB -> 6 blocks/CU.

__global__ __launch_bounds__(256) void gemm2_kernel(const float* __restrict__ X, const float* __restrict__ W,
      const float* __restrict__ a, float* __restrict__ H,
      float* __restrict__ svec, float* __restrict__ dvec, int n){
  __shared__ float xs[64 * SX2];  // 17408 B
  __shared__ float ws[64 * 32];   // 8192 B
  int tid = threadIdx.x;
  int r0 = blockIdx.x * 64;
  int tr = tid >> 4;
  int tc = tid & 15;

  #pragma unroll
  for (int p = 0; p < 4; p++){
    int lin = p * 256 + tid;       // 0..1023
    int row = lin >> 4;            // 0..63
    int c4 = lin & 15;             // 0..15
    int gr = r0 + row;
    float4 v = make_float4(0.f, 0.f, 0.f, 0.f);
    if (gr < n) v = *(const float4*)(X + (size_t)gr * HID + c4 * 4);
    *(float4*)(xs + row * SX2 + c4 * 4) = v;
  }
  #pragma unroll
  for (int p = 0; p < 2; p++){
    int lin = p * 256 + tid;       // 0..511
    int k = lin >> 3, c4 = lin & 7;
    *(float4*)(ws + k * 32 + c4 * 4) = *(const float4*)(W + (size_t)k * 32 + c4 * 4);
  }
  __syncthreads();

  float acc[4][2];
  #pragma unroll
  for (int i = 0; i < 4; i++){ acc[i][0] = 0.f; acc[i][1] = 0.f; }

  #pragma unroll
  for (int kq = 0; kq < 16; kq++){
    float xr[4][4];
    #pragma unroll
    for (int i = 0; i < 4; i++){
      float4 v = *(const float4*)(xs + (tr * 4 + i) * SX2 + kq * 4);
      xr[i][0] = v.x; xr[i][1] = v.y; xr[i][2] = v.z; xr[i][3] = v.w;
    }
    #pragma unroll
    for (int dk = 0; dk < 4; dk++){
      float2 w2 = *(const float2*)(ws + (size_t)(kq * 4 + dk) * 32 + tc * 2);
      #pragma unroll
      for (int i = 0; i < 4; i++){
        acc[i][0] = fmaf(xr[i][dk], w2.x, acc[i][0]);
        acc[i][1] = fmaf(xr[i][dk], w2.y, acc[i][1]);
      }
    }
  }

  float a0 = a[tc * 2], a1 = a[tc * 2 + 1];
  float b0 = a[32 + tc * 2], b1 = a[32 + tc * 2 + 1];
  float sp[4], dp[4];
  #pragma unroll
  for (int i = 0; i < 4; i++){
    sp[i] = fmaf(acc[i][0], a0, acc[i][1] * a1);
    dp[i] = fmaf(acc[i][0], b0, acc[i][1] * b1);
  }
  #pragma unroll
  for (int off = 1; off < 16; off <<= 1){
    #pragma unroll
    for (int i = 0; i < 4; i++){
      sp[i] += __shfl_xor(sp[i], off, 16);
      dp[i] += __shfl_xor(dp[i], off, 16);
    }
  }
  #pragma unroll
  for (int i = 0; i < 4; i++){
    int r = r0 + tr * 4 + i;
    if (r < n){
      *(float2*)(H + (size_t)r * NC + tc * 2) = make_float2(acc[i][0], acc[i][1]);
      if (tc == 0){ svec[r] = sp[i]; dvec[r] = dp[i]; }
    }
  }
}

// ---------------- Aggregate layer 1: chunked two-phase softmax + ELU, D=64, 16 lanes/node ----------------

__global__ __launch_bounds__(256) void agg1_kernel(const float* __restrict__ H, const float* __restrict__ sv,
      const float* __restrict__ dv, const int* __restrict__ row_ptr, const int* __restrict__ csr,
      float* __restrict__ out, int n){
  int t = blockIdx.x * 256 + threadIdx.x;
  int g = t >> 4, fl = t & 15;
  if (g >= n) return;
  int beg = row_ptr[g], end = row_ptr[g + 1];
  float si = sv[g];
  float m = INF_NEG, l = 0.f;
  float ox = 0.f, oy = 0.f, oz = 0.f, ow = 0.f;

  for (int cb = beg; cb < end; cb += 32){
    int ce = min(cb + 32, end);
    int e0 = cb + fl, e1 = cb + 16 + fl;
    int d0 = 0, d1 = 0;
    float ev0 = INF_NEG, ev1 = INF_NEG;
    if (e0 < ce){ d0 = csr[e0]; ev0 = lrelu(si + dv[d0]); }
    if (e1 < ce){ d1 = csr[e1]; ev1 = lrelu(si + dv[d1]); }
    float lm = fmaxf(ev0, ev1);
    #pragma unroll
    for (int off = 1; off < 16; off <<= 1) lm = fmaxf(lm, __shfl_xor(lm, off, 16));
    float nm = fmaxf(m, lm);
    float alpha = __expf(m - nm);
    m = nm;
    ev0 = __expf(ev0 - nm);
    ev1 = __expf(ev1 - nm);
    float ll = ev0 + ev1;
    #pragma unroll
    for (int off = 1; off < 16; off <<= 1) ll += __shfl_xor(ll, off, 16);
    l = l * alpha + ll;
    ox *= alpha; oy *= alpha; oz *= alpha; ow *= alpha;
    #pragma unroll
    for (int jj = 0; jj < 16; jj++){
      int e = cb + jj;
      if (e >= ce) break;
      float wgt = __shfl(ev0, jj, 16);
      int dd = __shfl(d0, jj, 16);
      float4 v = *(const float4*)(H + (size_t)dd * 64 + fl * 4);
      ox = fmaf(wgt, v.x, ox); oy = fmaf(wgt, v.y, oy);
      oz = fmaf(wgt, v.z, oz); ow = fmaf(wgt, v.w, ow);
    }
    #pragma unroll
    for (int jj = 0; jj < 16; jj++){
      int e = cb + 16 + jj;
      if (e >= ce) break;
      float wgt = __shfl(ev1, jj, 16);
      int dd = __shfl(d1, jj, 16);
      float4 v = *(const float4*)(H + (size_t)dd * 64 + fl * 4);
      ox = fmaf(wgt, v.x, ox); oy = fmaf(wgt, v.y, oy);
      oz = fmaf(wgt, v.z, oz); ow = fmaf(wgt, v.w, ow);
    }
  }
  float inv = (l > 0.f) ? 1.f / l : 0.f;
  ox *= inv; oy *= inv; oz *= inv; ow *= inv;
  ox = ox > 0.f ? ox : __expf(ox) - 1.f;
  oy = oy > 0.f ? oy : __expf(oy) - 1.f;
  oz = oz > 0.f ? oz : __expf(oz) - 1.f;
  ow = ow > 0.f ? ow : __expf(ow) - 1.f;
  *(float4*)(out + (size_t)g * 64 + fl * 4) = make_float4(ox, oy, oz, ow);
}

// ---------------- Aggregate layer 2: chunked two-phase softmax + log_softmax, D=32, 8 lanes/node ----------------

__global__ __launch_bounds__(256) void agg2_kernel(const float* __restrict__ H, const float* __restrict__ sv,
      const float* __restrict__ dv, const int* __restrict__ row_ptr, const int* __restrict__ csr,
      float* __restrict__ out, int n){
  int t = blockIdx.x * 256 + threadIdx.x;
  int g = t >> 3, fl = t & 7;
  if (g >= n) return;
  int beg = row_ptr[g], end = row_ptr[g + 1];
  float si = sv[g];
  float m = INF_NEG, l = 0.f;
  float ox = 0.f, oy = 0.f, oz = 0.f, ow = 0.f;

  for (int cb = beg; cb < end; cb += 32){
    int ce = min(cb + 32, end);
    float ev[4]; int dd4[4];
    float lm = INF_NEG;
    #pragma unroll
    for (int s = 0; s < 4; s++){
      int e = cb + s * 8 + fl;
      ev[s] = INF_NEG; dd4[s] = 0;
      if (e < ce){ dd4[s] = csr[e]; ev[s] = lrelu(si + dv[dd4[s]]); }
      lm = fmaxf(lm, ev[s]);
    }
    #pragma unroll
    for (int off = 1; off < 8; off <<= 1) lm = fmaxf(lm, __shfl_xor(lm, off, 8));
    float nm = fmaxf(m, lm);
    float alpha = __expf(m - nm);
    m = nm;
    float ll = 0.f;
    #pragma unroll
    for (int s = 0; s < 4; s++){ ev[s] = __expf(ev[s] - nm); ll += ev[s]; }
    #pragma unroll
    for (int off = 1; off < 8; off <<= 1) ll += __shfl_xor(ll, off, 8);
    l = l * alpha + ll;
    ox *= alpha; oy *= alpha; oz *= alpha; ow *= alpha;
    #pragma unroll
    for (int s = 0; s < 4; s++){
      #pragma unroll
      for (int jj = 0; jj < 8; jj++){
        int e = cb + s * 8 + jj;
        if (e >= ce) break;
        float wgt = __shfl(ev[s], jj, 8);
        int dd = __shfl(dd4[s], jj, 8);
        float4 v = *(const float4*)(H + (size_t)dd * 32 + fl * 4);
        ox = fmaf(wgt, v.x, ox); oy = fmaf(wgt, v.y, oy);
        oz = fmaf(wgt, v.z, oz); ow = fmaf(wgt, v.w, ow);
      }
    }
  }
  float inv = (l > 0.f) ? 1.f / l : 0.f;
  ox *= inv; oy *= inv; oz *= inv; ow *= inv;
  float tm = fmaxf(fmaxf(ox, oy), fmaxf(oz, ow));
  #pragma unroll
  for (int off = 1; off < 8; off <<= 1) tm = fmaxf(tm, __shfl_xor(tm, off, 8));
  float se = __expf(ox - tm) + __expf(oy - tm) + __expf(oz - tm) + __expf(ow - tm);
  #pragma unroll
  for (int off = 1; off < 8; off <<= 1) se += __shfl_xor(se, off, 8);
  float lg = tm + __logf(se);
  *(float4*)(out + (size_t)g * 32 + fl * 4) = make_float4(ox - lg, oy - lg, oz - lg, ow - lg);
}

// ---------------- launch ----------------

extern "C" void kernel_launch(void* const* d_in, const int* in_sizes, int n_in,
                              void* d_out, int out_size, void* d_ws, size_t ws_size,
                              hipStream_t stream) {
  (void)n_in; (void)out_size; (void)ws_size;
  const float* X  = (const float*)d_in[0];
  const int*   EI = (const int*)d_in[1];
  const float* W1 = (const float*)d_in[2];
  const float* W2 = (const float*)d_in[3];
  const float* A1 = (const float*)d_in[4];
  const float* A2 = (const float*)d_in[5];
  float* out = (float*)d_out;

  int N = in_sizes[0] / IN_DIM;
  int E = in_sizes[1] / 2;
  const int* src = EI;
  const int* dst = EI + E;

  auto align_up = [](size_t x){ return (x + 511) & ~(size_t)511; };
  char* w = (char*)d_ws;
  int* counts  = (int*)w;   w += align_up((size_t)N * 4);          // fallback fill only
  int* cursor  = (int*)w;   w += align_up((size_t)MAXNBK * 4);
  int* bbase   = (int*)w;   w += align_up((size_t)MAXNBK * 4);
  int* row_ptr = (int*)w;   w += align_up((size_t)(N + 1) * 4);
  int* bsums   = (int*)w;   w += align_up(1024);
  int* csr     = (int*)w;   w += align_up((size_t)E * 4);
  float* H1    = (float*)w; w += align_up((size_t)N * 64 * 4);
  float* hid   = (float*)w; w += align_up((size_t)N * 64 * 4);
  float* s1    = (float*)w; w += align_up((size_t)N * 4);
  float* d1    = (float*)w; w += align_up((size_t)N * 4);
  float* s2    = (float*)w; w += align_up((size_t)N * 4);
  float* d2    = (float*)w; w += align_up((size_t)N * 4);
  float* H2    = H1;                       // H1 dead after agg1; reuse
  unsigned int* tmp = (unsigned int*)hid;  // hid dead until agg1; nbk*SLOT*4 <= N*64*4

  int nbk = ceil_div(N, 256);

  if (N <= (1 << 17) && nbk <= MAXNBK && (size_t)nbk * SLOT <= (size_t)N * 64){
    hipMemsetAsync(cursor, 0, (size_t)nbk * 4, stream);
    bin_kernel<<<ceil_div(E, BIN_CHUNK), 256, 0, stream>>>(src, dst, cursor, tmp, E, nbk);
    bucket_base_kernel<<<1, 512, 0, stream>>>(cursor, bbase, nbk);
    bucket_scatter_kernel<<<nbk, 256, 0, stream>>>(tmp, cursor, bbase, row_ptr, csr, N);
  } else {
    int nb = ceil_div(N, 1024);
    hipMemsetAsync(counts, 0, (size_t)N * 4, stream);
    hist_kernel<<<ceil_div(E, 256), 256, 0, stream>>>(src, counts, E);
    scan_blocks_kernel<<<nb, 256, 0, stream>>>(counts, row_ptr, bsums, N);
    scan_sums_kernel<<<1, 256, 0, stream>>>(bsums, row_ptr, nb, N, E);
    add_offsets_kernel<<<nb, 1024, 0, stream>>>(row_ptr, bsums, N);
    hipMemsetAsync(counts, 0, (size_t)N * 4, stream);
    scatter_kernel<<<ceil_div(E, 256), 256, 0, stream>>>(src, dst, row_ptr, counts, csr, E);
  }

  gemm1_kernel<<<ceil_div(N, 64), 256, 0, stream>>>(X, W1, A1, H1, s1, d1, N);
  agg1_kernel<<<ceil_div(N * 16, 256), 256, 0, stream>>>(H1, s1, d1, row_ptr, csr, hid, N);
  gemm2_kernel<<<ceil_div(N, 64), 256, 0, stream>>>(hid, W2, A2, H2, s2, d2, N);
  agg2_kernel<<<ceil_div(N * 8, 256), 256, 0, stream>>>(H2, s2, d2, row_ptr, csr, out, N);
}

// Round 6
// 354.439 us; speedup vs baseline: 1.2651x; 1.0430x over previous
//
#include <hip/hip_runtime.h>
#include <math.h>

#define IN_DIM 256
#define HID 64
#define NC 32
#define NEG 0.01f
#define INF_NEG -1e30f
#define SX 36       // X tile stride (words), BK=32: 16B rows + 4-word pad rotates banks
#define SX2 68      // gemm2 full-K tile stride (words): 64 + 4 pad
#define MAXNBK 512  // max buckets (N <= 131072 for 17-bit dst packing)
#define SLOT 8256   // per-bucket tmp capacity; 33KB stride breaks L2 set aliasing
#define BCAP 12288  // bucket scatter LDS capacity (entries)
#define BIN_CHUNK 4096  // 391 blocks (1.5/CU) + 31KB LDS (5 blocks/CU)

static inline int ceil_div(int a, int b){ return (a + b - 1) / b; }

static __device__ __forceinline__ float lrelu(float x){ return x > 0.f ? x : NEG * x; }

// ---------------- CSR build ----------------

// Phase A: bucket edges by src>>8 into fixed slots tmp[b*SLOT ...], entry = (src&255)<<17 | dst.
// LDS-reorders each chunk bucket-contiguously so global writes are coalesced runs.
__global__ __launch_bounds__(256) void bin_kernel(const int* __restrict__ src,
      const int* __restrict__ dst, int* __restrict__ cursor,
      unsigned int* __restrict__ tmp, int E, int nbk){
  __shared__ unsigned int payload[BIN_CHUNK];
  __shared__ unsigned short bid[BIN_CHUNK];
  __shared__ int cnt[MAXNBK];
  __shared__ int lofs[MAXNBK];
  __shared__ int gbase[MAXNBK];
  __shared__ int s2[256];
  int tid = threadIdx.x;
  int beg = blockIdx.x * BIN_CHUNK;
  int end = min(E, beg + BIN_CHUNK);
  int len = end - beg;

  for (int i = tid; i < MAXNBK; i += 256) cnt[i] = 0;
  __syncthreads();
  for (int e = beg + tid; e < end; e += 256)
    atomicAdd(&cnt[src[e] >> 8], 1);
  __syncthreads();
  // exclusive scan of cnt[0..511] (2 elems/thread)
  int a0 = cnt[2 * tid], a1 = cnt[2 * tid + 1];
  int pair = a0 + a1;
  s2[tid] = pair; __syncthreads();
  int val = pair;
  for (int off = 1; off < 256; off <<= 1){
    int add = (tid >= off) ? s2[tid - off] : 0;
    __syncthreads();
    val += add; s2[tid] = val;
    __syncthreads();
  }
  int ep = val - pair;
  lofs[2 * tid] = ep;
  lofs[2 * tid + 1] = ep + a0;
  __syncthreads();
  // reserve global runs, reset cnt as rank counters
  for (int i = tid; i < nbk; i += 256){
    int c = cnt[i];
    gbase[i] = (c > 0) ? atomicAdd(&cursor[i], c) : 0;
  }
  __syncthreads();
  for (int i = tid; i < MAXNBK; i += 256) cnt[i] = 0;
  __syncthreads();
  // reorder into LDS bucket-contiguously
  for (int e = beg + tid; e < end; e += 256){
    int s = src[e];
    int b = s >> 8;
    int r = atomicAdd(&cnt[b], 1);
    int pos = lofs[b] + r;
    payload[pos] = ((unsigned)(s & 255) << 17) | (unsigned)dst[e];
    bid[pos] = (unsigned short)b;
  }
  __syncthreads();
  // coalesced run writes
  for (int pos = tid; pos < len; pos += 256){
    int b = bid[pos];
    int idx = pos - lofs[b];
    int g = gbase[b] + idx;
    if (g < SLOT) tmp[(size_t)b * SLOT + g] = payload[pos];
  }
}

// Phase B: exclusive scan of bucket counts -> bucket segment bases. One block.
__global__ __launch_bounds__(512) void bucket_base_kernel(const int* __restrict__ cursor,
      int* __restrict__ bbase, int nbk){
  __shared__ int sh[512];
  int tid = threadIdx.x;
  int v = (tid < nbk) ? min(cursor[tid], SLOT) : 0;
  sh[tid] = v; __syncthreads();
  int val = v;
  for (int off = 1; off < 512; off <<= 1){
    int add = (tid >= off) ? sh[tid - off] : 0;
    __syncthreads();
    val += add; sh[tid] = val;
    __syncthreads();
  }
  if (tid < nbk) bbase[tid] = val - v;
}

// Phase C: one block per bucket; derive row_ptr, scatter to exact positions in LDS,
// write csr coalesced.
__global__ __launch_bounds__(256) void bucket_scatter_kernel(const unsigned int* __restrict__ tmp,
      const int* __restrict__ cursor, const int* __restrict__ bbase,
      int* __restrict__ row_ptr, int* __restrict__ csr, int n){
  __shared__ int cnt[256];
  __shared__ int cur[256];
  __shared__ int lbuf[BCAP];
  int tid = threadIdx.x;
  int b = blockIdx.x;
  int n0 = b << 8;
  int nn = min(256, n - n0);
  int len = min(cursor[b], SLOT);
  int segb = bbase[b];
  const unsigned int* T = tmp + (size_t)b * SLOT;
  cnt[tid] = 0;
  __syncthreads();
  for (int e = tid; e < len; e += 256) atomicAdd(&cnt[T[e] >> 17], 1);
  __syncthreads();
  int tv = cnt[tid];
  int val = tv;
  for (int off = 1; off < 256; off <<= 1){
    int add = (tid >= off) ? cnt[tid - off] : 0;
    __syncthreads();
    val += add; cnt[tid] = val;
    __syncthreads();
  }
  int excl = val - tv;
  cur[tid] = excl;
  if (tid < nn) row_ptr[n0 + tid] = segb + excl;
  if (n0 + nn == n && tid == 0) row_ptr[n] = segb + len;
  __syncthreads();
  if (len <= BCAP){
    for (int e = tid; e < len; e += 256){
      unsigned v = T[e];
      int pos = atomicAdd(&cur[v >> 17], 1);
      lbuf[pos] = (int)(v & 0x1FFFF);
    }
    __syncthreads();
    for (int e = tid; e < len; e += 256) csr[segb + e] = lbuf[e];
  } else {
    for (int e = tid; e < len; e += 256){
      unsigned v = T[e];
      int pos = atomicAdd(&cur[v >> 17], 1);
      csr[segb + pos] = (int)(v & 0x1FFFF);
    }
  }
}

// ---- fallback CSR path (N > 2^17 only; never hit at this problem size) ----

__global__ void hist_kernel(const int* __restrict__ src, int* __restrict__ counts, int E){
  int i = blockIdx.x * blockDim.x + threadIdx.x;
  if (i < E) atomicAdd(&counts[src[i]], 1);
}
__global__ void scan_blocks_kernel(const int* __restrict__ counts, int* __restrict__ excl,
                                   int* __restrict__ bsums, int n){
  __shared__ int sh[256];
  int tid = threadIdx.x;
  int base = blockIdx.x * 1024 + tid * 4;
  int c[4]; int tsum = 0;
  #pragma unroll
  for (int j = 0; j < 4; j++){ int i = base + j; c[j] = (i < n) ? counts[i] : 0; tsum += c[j]; }
  sh[tid] = tsum; __syncthreads();
  int val = tsum;
  for (int off = 1; off < 256; off <<= 1){
    int add = (tid >= off) ? sh[tid - off] : 0;
    __syncthreads();
    val += add; sh[tid] = val;
    __syncthreads();
  }
  int p = val - tsum;
  #pragma unroll
  for (int j = 0; j < 4; j++){ int i = base + j; if (i < n) excl[i] = p; p += c[j]; }
  if (tid == 255) bsums[blockIdx.x] = val;
}
__global__ void scan_sums_kernel(int* __restrict__ bsums, int* __restrict__ row_ptr,
                                 int nb, int n, int E){
  __shared__ int sh[256];
  int tid = threadIdx.x;
  int v = (tid < nb) ? bsums[tid] : 0;
  sh[tid] = v; __syncthreads();
  int val = v;
  for (int off = 1; off < 256; off <<= 1){
    int add = (tid >= off) ? sh[tid - off] : 0;
    __syncthreads();
    val += add; sh[tid] = val;
    __syncthreads();
  }
  if (tid < nb) bsums[tid] = val - v;
  if (tid == 0) row_ptr[n] = E;
}
__global__ void add_offsets_kernel(int* __restrict__ excl, const int* __restrict__ bsums, int n){
  int i = blockIdx.x * 1024 + threadIdx.x;
  if (i < n) excl[i] += bsums[blockIdx.x];
}
__global__ void scatter_kernel(const int* __restrict__ src, const int* __restrict__ dst,
                               const int* __restrict__ row_ptr, int* __restrict__ fill,
                               int* __restrict__ csr, int E){
  int i = blockIdx.x * blockDim.x + threadIdx.x;
  if (i >= E) return;
  int s = src[i];
  int pos = row_ptr[s] + atomicAdd(&fill[s], 1);
  csr[pos] = dst[i];
}

// ---------------- GEMM 1: X[N,256] @ W1[256,64] -> H, s, d ----------------
// R2 config (measured 77us, VGPR 44): BM=64, 4x4 tile, BK=32, xs+ws in LDS,
// dual register prefetch, 2 barriers/kb, grid 1563 fully resident. FROZEN.

__global__ __launch_bounds__(256) void gemm1_kernel(const float* __restrict__ X, const float* __restrict__ W,
      const float* __restrict__ a, float* __restrict__ H,
      float* __restrict__ svec, float* __restrict__ dvec, int n){
  __shared__ float xs[64 * SX];   // 9216 B
  __shared__ float ws[32 * 64];   // 8192 B
  int tid = threadIdx.x;
  int r0 = blockIdx.x * 64;
  int tr = tid >> 4;              // 16 row-groups x 4 rows
  int tc = tid & 15;              // 16 col-groups x 4 cols
  int srow = tid >> 3, sc8 = tid & 7;   // staging: 32 rows/pass x 8 float4 chunks

  float4 pfx[2], pfw[2];
  #pragma unroll
  for (int p = 0; p < 2; p++){
    int row = p * 32 + srow;
    int gr = r0 + row;
    pfx[p] = make_float4(0.f, 0.f, 0.f, 0.f);
    if (gr < n) pfx[p] = *(const float4*)(X + (size_t)gr * IN_DIM + sc8 * 4);
  }
  #pragma unroll
  for (int p = 0; p < 2; p++){
    int idx = p * 256 + tid;
    int k = idx >> 4, c4 = idx & 15;
    pfw[p] = *(const float4*)(W + (size_t)k * 64 + c4 * 4);
  }

  float acc[4][4];
  #pragma unroll
  for (int i = 0; i < 4; i++)
    #pragma unroll
    for (int j = 0; j < 4; j++) acc[i][j] = 0.f;

  for (int kb = 0; kb < 8; kb++){
    __syncthreads();
    #pragma unroll
    for (int p = 0; p < 2; p++){
      int row = p * 32 + srow;
      *(float4*)(xs + row * SX + sc8 * 4) = pfx[p];
    }
    #pragma unroll
    for (int p = 0; p < 2; p++){
      int idx = p * 256 + tid;
      int k = idx >> 4, c4 = idx & 15;
      *(float4*)(ws + k * 64 + c4 * 4) = pfw[p];
    }
    if (kb < 7){
      #pragma unroll
      for (int p = 0; p < 2; p++){
        int row = p * 32 + srow;
        int gr = r0 + row;
        pfx[p] = make_float4(0.f, 0.f, 0.f, 0.f);
        if (gr < n) pfx[p] = *(const float4*)(X + (size_t)gr * IN_DIM + (kb + 1) * 32 + sc8 * 4);
      }
      #pragma unroll
      for (int p = 0; p < 2; p++){
        int idx = p * 256 + tid;
        int k = idx >> 4, c4 = idx & 15;
        pfw[p] = *(const float4*)(W + (size_t)((kb + 1) * 32 + k) * 64 + c4 * 4);
      }
    }
    __syncthreads();
    #pragma unroll
    for (int kq = 0; kq < 8; kq++){
      float xr[4][4];
      #pragma unroll
      for (int i = 0; i < 4; i++){
        float4 v = *(const float4*)(xs + (tr * 4 + i) * SX + kq * 4);
        xr[i][0] = v.x; xr[i][1] = v.y; xr[i][2] = v.z; xr[i][3] = v.w;
      }
      #pragma unroll
      for (int dk = 0; dk < 4; dk++){
        float4 w4 = *(const float4*)(ws + (size_t)(kq * 4 + dk) * 64 + tc * 4);
        float wv[4] = {w4.x, w4.y, w4.z, w4.w};
        #pragma unroll
        for (int i = 0; i < 4; i++)
          #pragma unroll
          for (int j = 0; j < 4; j++) acc[i][j] = fmaf(xr[i][dk], wv[j], acc[i][j]);
      }
    }
  }

  float av[4], bv[4];
  #pragma unroll
  for (int j = 0; j < 4; j++){ av[j] = a[tc * 4 + j]; bv[j] = a[64 + tc * 4 + j]; }
  float sp[4], dp[4];
  #pragma unroll
  for (int i = 0; i < 4; i++){
    float s = 0.f, d = 0.f;
    #pragma unroll
    for (int j = 0; j < 4; j++){ s = fmaf(acc[i][j], av[j], s); d = fmaf(acc[i][j], bv[j], d); }
    sp[i] = s; dp[i] = d;
  }
  #pragma unroll
  for (int off = 1; off < 16; off <<= 1){
    #pragma unroll
    for (int i = 0; i < 4; i++){
      sp[i] += __shfl_xor(sp[i], off, 16);
      dp[i] += __shfl_xor(dp[i], off, 16);
    }
  }
  #pragma unroll
  for (int i = 0; i < 4; i++){
    int r = r0 + tr * 4 + i;
    if (r < n){
      *(float4*)(H + (size_t)r * 64 + tc * 4) = make_float4(acc[i][0], acc[i][1], acc[i][2], acc[i][3]);
      if (tc == 0){ svec[r] = sp[i]; dvec[r] = dp[i]; }
    }
  }
}

// ---------------- GEMM 2: hid[N,64] @ W2[64,32] -> H2, s, d ----------------
// BM=64, thread owns 4x2. K=64 staged once, ONE barrier, barrier-free compute.

__global__ __launch_bounds__(256) void gemm2_kernel(const float* __restrict__ X, const float* __restrict__ W,
      const float* __restrict__ a, float* __restrict__ H,
      float* __restrict__ svec, float* __restrict__ dvec, int n){
  __shared__ float xs[64 * SX2];  // 17408 B
  __shared__ float ws[64 * 32];   // 8192 B
  int tid = threadIdx.x;
  int r0 = blockIdx.x * 64;
  int tr = tid >> 4;
  int tc = tid & 15;

  #pragma unroll
  for (int p = 0; p < 4; p++){
    int lin = p * 256 + tid;       // 0..1023
    int row = lin >> 4;            // 0..63
    int c4 = lin & 15;             // 0..15
    int gr = r0 + row;
    float4 v = make_float4(0.f, 0.f, 0.f, 0.f);
    if (gr < n) v = *(const float4*)(X + (size_t)gr * HID + c4 * 4);
    *(float4*)(xs + row * SX2 + c4 * 4) = v;
  }
  #pragma unroll
  for (int p = 0; p < 2; p++){
    int lin = p * 256 + tid;       // 0..511
    int k = lin >> 3, c4 = lin & 7;
    *(float4*)(ws + k * 32 + c4 * 4) = *(const float4*)(W + (size_t)k * 32 + c4 * 4);
  }
  __syncthreads();

  float acc[4][2];
  #pragma unroll
  for (int i = 0; i < 4; i++){ acc[i][0] = 0.f; acc[i][1] = 0.f; }

  #pragma unroll
  for (int kq = 0; kq < 16; kq++){
    float xr[4][4];
    #pragma unroll
    for (int i = 0; i < 4; i++){
      float4 v = *(const float4*)(xs + (tr * 4 + i) * SX2 + kq * 4);
      xr[i][0] = v.x; xr[i][1] = v.y; xr[i][2] = v.z; xr[i][3] = v.w;
    }
    #pragma unroll
    for (int dk = 0; dk < 4; dk++){
      float2 w2 = *(const float2*)(ws + (size_t)(kq * 4 + dk) * 32 + tc * 2);
      #pragma unroll
      for (int i = 0; i < 4; i++){
        acc[i][0] = fmaf(xr[i][dk], w2.x, acc[i][0]);
        acc[i][1] = fmaf(xr[i][dk], w2.y, acc[i][1]);
      }
    }
  }

  float a0 = a[tc * 2], a1 = a[tc * 2 + 1];
  float b0 = a[32 + tc * 2], b1 = a[32 + tc * 2 + 1];
  float sp[4], dp[4];
  #pragma unroll
  for (int i = 0; i < 4; i++){
    sp[i] = fmaf(acc[i][0], a0, acc[i][1] * a1);
    dp[i] = fmaf(acc[i][0], b0, acc[i][1] * b1);
  }
  #pragma unroll
  for (int off = 1; off < 16; off <<= 1){
    #pragma unroll
    for (int i = 0; i < 4; i++){
      sp[i] += __shfl_xor(sp[i], off, 16);
      dp[i] += __shfl_xor(dp[i], off, 16);
    }
  }
  #pragma unroll
  for (int i = 0; i < 4; i++){
    int r = r0 + tr * 4 + i;
    if (r < n){
      *(float2*)(H + (size_t)r * NC + tc * 2) = make_float2(acc[i][0], acc[i][1]);
      if (tc == 0){ svec[r] = sp[i]; dvec[r] = dp[i]; }
    }
  }
}

// ---------------- Aggregate layer 1: chunked two-phase softmax + ELU, D=64, 16 lanes/node ----------------
// PV inner loops: NO break -- invalid edges carry weight exactly 0 (exp(INF_NEG-nm))
// and dd=0, so all 16 gathers issue unconditionally back-to-back (ILP hides L2/L3
// latency instead of serializing on the early-exit branch). Second 16-block guarded
// (mean degree = 16, so it usually doesn't run).

__global__ __launch_bounds__(256) void agg1_kernel(const float* __restrict__ H, const float* __restrict__ sv,
      const float* __restrict__ dv, const int* __restrict__ row_ptr, const int* __restrict__ csr,
      float* __restrict__ out, int n){
  int t = blockIdx.x * 256 + threadIdx.x;
  int g = t >> 4, fl = t & 15;
  if (g >= n) return;
  int beg = row_ptr[g], end = row_ptr[g + 1];
  float si = sv[g];
  float m = INF_NEG, l = 0.f;
  float ox = 0.f, oy = 0.f, oz = 0.f, ow = 0.f;

  for (int cb = beg; cb < end; cb += 32){
    int ce = min(cb + 32, end);
    int e0 = cb + fl, e1 = cb + 16 + fl;
    int d0 = 0, d1 = 0;
    float ev0 = INF_NEG, ev1 = INF_NEG;
    if (e0 < ce){ d0 = csr[e0]; ev0 = lrelu(si + dv[d0]); }
    if (e1 < ce){ d1 = csr[e1]; ev1 = lrelu(si + dv[d1]); }
    float lm = fmaxf(ev0, ev1);
    #pragma unroll
    for (int off = 1; off < 16; off <<= 1) lm = fmaxf(lm, __shfl_xor(lm, off, 16));
    float nm = fmaxf(m, lm);
    float alpha = __expf(m - nm);
    m = nm;
    ev0 = __expf(ev0 - nm);   // exactly 0 for invalid edges
    ev1 = __expf(ev1 - nm);
    float ll = ev0 + ev1;
    #pragma unroll
    for (int off = 1; off < 16; off <<= 1) ll += __shfl_xor(ll, off, 16);
    l = l * alpha + ll;
    ox *= alpha; oy *= alpha; oz *= alpha; ow *= alpha;
    #pragma unroll
    for (int jj = 0; jj < 16; jj++){
      float wgt = __shfl(ev0, jj, 16);
      int dd = __shfl(d0, jj, 16);
      float4 v = *(const float4*)(H + (size_t)dd * 64 + fl * 4);
      ox = fmaf(wgt, v.x, ox); oy = fmaf(wgt, v.y, oy);
      oz = fmaf(wgt, v.z, oz); ow = fmaf(wgt, v.w, ow);
    }
    if (ce - cb > 16){
      #pragma unroll
      for (int jj = 0; jj < 16; jj++){
        float wgt = __shfl(ev1, jj, 16);
        int dd = __shfl(d1, jj, 16);
        float4 v = *(const float4*)(H + (size_t)dd * 64 + fl * 4);
        ox = fmaf(wgt, v.x, ox); oy = fmaf(wgt, v.y, oy);
        oz = fmaf(wgt, v.z, oz); ow = fmaf(wgt, v.w, ow);
      }
    }
  }
  float inv = (l > 0.f) ? 1.f / l : 0.f;
  ox *= inv; oy *= inv; oz *= inv; ow *= inv;
  ox = ox > 0.f ? ox : __expf(ox) - 1.f;
  oy = oy > 0.f ? oy : __expf(oy) - 1.f;
  oz = oz > 0.f ? oz : __expf(oz) - 1.f;
  ow = ow > 0.f ? ow : __expf(ow) - 1.f;
  *(float4*)(out + (size_t)g * 64 + fl * 4) = make_float4(ox, oy, oz, ow);
}

// ---------------- Aggregate layer 2: chunked two-phase softmax + log_softmax, D=32, 8 lanes/node ----------------
// Same no-break predicated PV structure; each 8-block guarded.

__global__ __launch_bounds__(256) void agg2_kernel(const float* __restrict__ H, const float* __restrict__ sv,
      const float* __restrict__ dv, const int* __restrict__ row_ptr, const int* __restrict__ csr,
      float* __restrict__ out, int n){
  int t = blockIdx.x * 256 + threadIdx.x;
  int g = t >> 3, fl = t & 7;
  if (g >= n) return;
  int beg = row_ptr[g], end = row_ptr[g + 1];
  float si = sv[g];
  float m = INF_NEG, l = 0.f;
  float ox = 0.f, oy = 0.f, oz = 0.f, ow = 0.f;

  for (int cb = beg; cb < end; cb += 32){
    int ce = min(cb + 32, end);
    float ev[4]; int dd4[4];
    float lm = INF_NEG;
    #pragma unroll
    for (int s = 0; s < 4; s++){
      int e = cb + s * 8 + fl;
      ev[s] = INF_NEG; dd4[s] = 0;
      if (e < ce){ dd4[s] = csr[e]; ev[s] = lrelu(si + dv[dd4[s]]); }
      lm = fmaxf(lm, ev[s]);
    }
    #pragma unroll
    for (int off = 1; off < 8; off <<= 1) lm = fmaxf(lm, __shfl_xor(lm, off, 8));
    float nm = fmaxf(m, lm);
    float alpha = __expf(m - nm);
    m = nm;
    float ll = 0.f;
    #pragma unroll
    for (int s = 0; s < 4; s++){ ev[s] = __expf(ev[s] - nm); ll += ev[s]; }   // 0 for invalid
    #pragma unroll
    for (int off = 1; off < 8; off <<= 1) ll += __shfl_xor(ll, off, 8);
    l = l * alpha + ll;
    ox *= alpha; oy *= alpha; oz *= alpha; ow *= alpha;
    #pragma unroll
    for (int s = 0; s < 4; s++){
      if (ce - cb > s * 8){
        #pragma unroll
        for (int jj = 0; jj < 8; jj++){
          float wgt = __shfl(ev[s], jj, 8);
          int dd = __shfl(dd4[s], jj, 8);
          float4 v = *(const float4*)(H + (size_t)dd * 32 + fl * 4);
          ox = fmaf(wgt, v.x, ox); oy = fmaf(wgt, v.y, oy);
          oz = fmaf(wgt, v.z, oz); ow = fmaf(wgt, v.w, ow);
        }
      }
    }
  }
  float inv = (l > 0.f) ? 1.f / l : 0.f;
  ox *= inv; oy *= inv; oz *= inv; ow *= inv;
  float tm = fmaxf(fmaxf(ox, oy), fmaxf(oz, ow));
  #pragma unroll
  for (int off = 1; off < 8; off <<= 1) tm = fmaxf(tm, __shfl_xor(tm, off, 8));
  float se = __expf(ox - tm) + __expf(oy - tm) + __expf(oz - tm) + __expf(ow - tm);
  #pragma unroll
  for (int off = 1; off < 8; off <<= 1) se += __shfl_xor(se, off, 8);
  float lg = tm + __logf(se);
  *(float4*)(out + (size_t)g * 32 + fl * 4) = make_float4(ox - lg, oy - lg, oz - lg, ow - lg);
}

// ---------------- launch ----------------

extern "C" void kernel_launch(void* const* d_in, const int* in_sizes, int n_in,
                              void* d_out, int out_size, void* d_ws, size_t ws_size,
                              hipStream_t stream) {
  (void)n_in; (void)out_size; (void)ws_size;
  const float* X  = (const float*)d_in[0];
  const int*   EI = (const int*)d_in[1];
  const float* W1 = (const float*)d_in[2];
  const float* W2 = (const float*)d_in[3];
  const float* A1 = (const float*)d_in[4];
  const float* A2 = (const float*)d_in[5];
  float* out = (float*)d_out;

  int N = in_sizes[0] / IN_DIM;
  int E = in_sizes[1] / 2;
  const int* src = EI;
  const int* dst = EI + E;

  auto align_up = [](size_t x){ return (x + 511) & ~(size_t)511; };
  char* w = (char*)d_ws;
  int* counts  = (int*)w;   w += align_up((size_t)N * 4);          // fallback fill only
  int* cursor  = (int*)w;   w += align_up((size_t)MAXNBK * 4);
  int* bbase   = (int*)w;   w += align_up((size_t)MAXNBK * 4);
  int* row_ptr = (int*)w;   w += align_up((size_t)(N + 1) * 4);
  int* bsums   = (int*)w;   w += align_up(1024);
  int* csr     = (int*)w;   w += align_up((size_t)E * 4);
  float* H1    = (float*)w; w += align_up((size_t)N * 64 * 4);
  float* hid   = (float*)w; w += align_up((size_t)N * 64 * 4);
  float* s1    = (float*)w; w += align_up((size_t)N * 4);
  float* d1    = (float*)w; w += align_up((size_t)N * 4);
  float* s2    = (float*)w; w += align_up((size_t)N * 4);
  float* d2    = (float*)w; w += align_up((size_t)N * 4);
  float* H2    = H1;                       // H1 dead after agg1; reuse
  unsigned int* tmp = (unsigned int*)hid;  // hid dead until agg1; nbk*SLOT*4 <= N*64*4

  int nbk = ceil_div(N, 256);

  if (N <= (1 << 17) && nbk <= MAXNBK && (size_t)nbk * SLOT <= (size_t)N * 64){
    hipMemsetAsync(cursor, 0, (size_t)nbk * 4, stream);
    bin_kernel<<<ceil_div(E, BIN_CHUNK), 256, 0, stream>>>(src, dst, cursor, tmp, E, nbk);
    bucket_base_kernel<<<1, 512, 0, stream>>>(cursor, bbase, nbk);
    bucket_scatter_kernel<<<nbk, 256, 0, stream>>>(tmp, cursor, bbase, row_ptr, csr, N);
  } else {
    int nb = ceil_div(N, 1024);
    hipMemsetAsync(counts, 0, (size_t)N * 4, stream);
    hist_kernel<<<ceil_div(E, 256), 256, 0, stream>>>(src, counts, E);
    scan_blocks_kernel<<<nb, 256, 0, stream>>>(counts, row_ptr, bsums, N);
    scan_sums_kernel<<<1, 256, 0, stream>>>(bsums, row_ptr, nb, N, E);
    add_offsets_kernel<<<nb, 1024, 0, stream>>>(row_ptr, bsums, N);
    hipMemsetAsync(counts, 0, (size_t)N * 4, stream);
    scatter_kernel<<<ceil_div(E, 256), 256, 0, stream>>>(src, dst, row_ptr, counts, csr, E);
  }

  gemm1_kernel<<<ceil_div(N, 64), 256, 0, stream>>>(X, W1, A1, H1, s1, d1, N);
  agg1_kernel<<<ceil_div(N * 16, 256), 256, 0, stream>>>(H1, s1, d1, row_ptr, csr, hid, N);
  gemm2_kernel<<<ceil_div(N, 64), 256, 0, stream>>>(hid, W2, A2, H2, s2, d2, N);
  agg2_kernel<<<ceil_div(N * 8, 256), 256, 0, stream>>>(H2, s2, d2, row_ptr, csr, out, N);
}

// Round 7
// 351.309 us; speedup vs baseline: 1.2763x; 1.0089x over previous
//
#include <hip/hip_runtime.h>
#include <math.h>

#define IN_DIM 256
#define HID 64
#define NC 32
#define NEG 0.01f
#define INF_NEG -1e30f
#define SX 36       // X tile stride (words), BK=32: 16B rows + 4-word pad rotates banks
#define SX2 68      // gemm2 full-K tile stride (words): 64 + 4 pad
#define MAXNBK 512  // max buckets (N <= 131072 for 17-bit dst packing)
#define SLOT 8256   // per-bucket tmp capacity; 33KB stride breaks L2 set aliasing
#define BCAP 12288  // bucket scatter LDS capacity (entries)
#define BIN_CHUNK 4096  // 391 blocks (1.5/CU) + 31KB LDS (5 blocks/CU)

static inline int ceil_div(int a, int b){ return (a + b - 1) / b; }

static __device__ __forceinline__ float lrelu(float x){ return x > 0.f ? x : NEG * x; }

// ---------------- CSR build ----------------

// Phase A: bucket edges by src>>8 into fixed slots tmp[b*SLOT ...], entry = (src&255)<<17 | dst.
// LDS-reorders each chunk bucket-contiguously so global writes are coalesced runs.
__global__ __launch_bounds__(256) void bin_kernel(const int* __restrict__ src,
      const int* __restrict__ dst, int* __restrict__ cursor,
      unsigned int* __restrict__ tmp, int E, int nbk){
  __shared__ unsigned int payload[BIN_CHUNK];
  __shared__ unsigned short bid[BIN_CHUNK];
  __shared__ int cnt[MAXNBK];
  __shared__ int lofs[MAXNBK];
  __shared__ int gbase[MAXNBK];
  __shared__ int s2[256];
  int tid = threadIdx.x;
  int beg = blockIdx.x * BIN_CHUNK;
  int end = min(E, beg + BIN_CHUNK);
  int len = end - beg;

  for (int i = tid; i < MAXNBK; i += 256) cnt[i] = 0;
  __syncthreads();
  for (int e = beg + tid; e < end; e += 256)
    atomicAdd(&cnt[src[e] >> 8], 1);
  __syncthreads();
  // exclusive scan of cnt[0..511] (2 elems/thread)
  int a0 = cnt[2 * tid], a1 = cnt[2 * tid + 1];
  int pair = a0 + a1;
  s2[tid] = pair; __syncthreads();
  int val = pair;
  for (int off = 1; off < 256; off <<= 1){
    int add = (tid >= off) ? s2[tid - off] : 0;
    __syncthreads();
    val += add; s2[tid] = val;
    __syncthreads();
  }
  int ep = val - pair;
  lofs[2 * tid] = ep;
  lofs[2 * tid + 1] = ep + a0;
  __syncthreads();
  // reserve global runs, reset cnt as rank counters
  for (int i = tid; i < nbk; i += 256){
    int c = cnt[i];
    gbase[i] = (c > 0) ? atomicAdd(&cursor[i], c) : 0;
  }
  __syncthreads();
  for (int i = tid; i < MAXNBK; i += 256) cnt[i] = 0;
  __syncthreads();
  // reorder into LDS bucket-contiguously
  for (int e = beg + tid; e < end; e += 256){
    int s = src[e];
    int b = s >> 8;
    int r = atomicAdd(&cnt[b], 1);
    int pos = lofs[b] + r;
    payload[pos] = ((unsigned)(s & 255) << 17) | (unsigned)dst[e];
    bid[pos] = (unsigned short)b;
  }
  __syncthreads();
  // coalesced run writes
  for (int pos = tid; pos < len; pos += 256){
    int b = bid[pos];
    int idx = pos - lofs[b];
    int g = gbase[b] + idx;
    if (g < SLOT) tmp[(size_t)b * SLOT + g] = payload[pos];
  }
}

// Phase B: exclusive scan of bucket counts -> bucket segment bases. One block.
__global__ __launch_bounds__(512) void bucket_base_kernel(const int* __restrict__ cursor,
      int* __restrict__ bbase, int nbk){
  __shared__ int sh[512];
  int tid = threadIdx.x;
  int v = (tid < nbk) ? min(cursor[tid], SLOT) : 0;
  sh[tid] = v; __syncthreads();
  int val = v;
  for (int off = 1; off < 512; off <<= 1){
    int add = (tid >= off) ? sh[tid - off] : 0;
    __syncthreads();
    val += add; sh[tid] = val;
    __syncthreads();
  }
  if (tid < nbk) bbase[tid] = val - v;
}

// Phase C: one block per bucket; derive row_ptr, scatter to exact positions in LDS,
// write csr coalesced.
__global__ __launch_bounds__(256) void bucket_scatter_kernel(const unsigned int* __restrict__ tmp,
      const int* __restrict__ cursor, const int* __restrict__ bbase,
      int* __restrict__ row_ptr, int* __restrict__ csr, int n){
  __shared__ int cnt[256];
  __shared__ int cur[256];
  __shared__ int lbuf[BCAP];
  int tid = threadIdx.x;
  int b = blockIdx.x;
  int n0 = b << 8;
  int nn = min(256, n - n0);
  int len = min(cursor[b], SLOT);
  int segb = bbase[b];
  const unsigned int* T = tmp + (size_t)b * SLOT;
  cnt[tid] = 0;
  __syncthreads();
  for (int e = tid; e < len; e += 256) atomicAdd(&cnt[T[e] >> 17], 1);
  __syncthreads();
  int tv = cnt[tid];
  int val = tv;
  for (int off = 1; off < 256; off <<= 1){
    int add = (tid >= off) ? cnt[tid - off] : 0;
    __syncthreads();
    val += add; cnt[tid] = val;
    __syncthreads();
  }
  int excl = val - tv;
  cur[tid] = excl;
  if (tid < nn) row_ptr[n0 + tid] = segb + excl;
  if (n0 + nn == n && tid == 0) row_ptr[n] = segb + len;
  __syncthreads();
  if (len <= BCAP){
    for (int e = tid; e < len; e += 256){
      unsigned v = T[e];
      int pos = atomicAdd(&cur[v >> 17], 1);
      lbuf[pos] = (int)(v & 0x1FFFF);
    }
    __syncthreads();
    for (int e = tid; e < len; e += 256) csr[segb + e] = lbuf[e];
  } else {
    for (int e = tid; e < len; e += 256){
      unsigned v = T[e];
      int pos = atomicAdd(&cur[v >> 17], 1);
      csr[segb + pos] = (int)(v & 0x1FFFF);
    }
  }
}

// ---- fallback CSR path (N > 2^17 only; never hit at this problem size) ----

__global__ void hist_kernel(const int* __restrict__ src, int* __restrict__ counts, int E){
  int i = blockIdx.x * blockDim.x + threadIdx.x;
  if (i < E) atomicAdd(&counts[src[i]], 1);
}
__global__ void scan_blocks_kernel(const int* __restrict__ counts, int* __restrict__ excl,
                                   int* __restrict__ bsums, int n){
  __shared__ int sh[256];
  int tid = threadIdx.x;
  int base = blockIdx.x * 1024 + tid * 4;
  int c[4]; int tsum = 0;
  #pragma unroll
  for (int j = 0; j < 4; j++){ int i = base + j; c[j] = (i < n) ? counts[i] : 0; tsum += c[j]; }
  sh[tid] = tsum; __syncthreads();
  int val = tsum;
  for (int off = 1; off < 256; off <<= 1){
    int add = (tid >= off) ? sh[tid - off] : 0;
    __syncthreads();
    val += add; sh[tid] = val;
    __syncthreads();
  }
  int p = val - tsum;
  #pragma unroll
  for (int j = 0; j < 4; j++){ int i = base + j; if (i < n) excl[i] = p; p += c[j]; }
  if (tid == 255) bsums[blockIdx.x] = val;
}
__global__ void scan_sums_kernel(int* __restrict__ bsums, int* __restrict__ row_ptr,
                                 int nb, int n, int E){
  __shared__ int sh[256];
  int tid = threadIdx.x;
  int v = (tid < nb) ? bsums[tid] : 0;
  sh[tid] = v; __syncthreads();
  int val = v;
  for (int off = 1; off < 256; off <<= 1){
    int add = (tid >= off) ? sh[tid - off] : 0;
    __syncthreads();
    val += add; sh[tid] = val;
    __syncthreads();
  }
  if (tid < nb) bsums[tid] = val - v;
  if (tid == 0) row_ptr[n] = E;
}
__global__ void add_offsets_kernel(int* __restrict__ excl, const int* __restrict__ bsums, int n){
  int i = blockIdx.x * 1024 + threadIdx.x;
  if (i < n) excl[i] += bsums[blockIdx.x];
}
__global__ void scatter_kernel(const int* __restrict__ src, const int* __restrict__ dst,
                               const int* __restrict__ row_ptr, int* __restrict__ fill,
                               int* __restrict__ csr, int E){
  int i = blockIdx.x * blockDim.x + threadIdx.x;
  if (i >= E) return;
  int s = src[i];
  int pos = row_ptr[s] + atomicAdd(&fill[s], 1);
  csr[pos] = dst[i];
}

// ---------------- GEMM 1: X[N,256] @ W1[256,64] -> H, s, d ----------------
// v7: BM=64, grid 1563 (fully resident), 256 threads as TWO k-halves of 128.
// Each half-thread owns a 4x8 tile (rows rg*4.., cols cg*8..) and processes
// 4 of the 8 kq per staged 32-k tile (half h: kq = h*4..h*4+3). DS instr/kq
// drops 16->12 per 128 FMA (DS-pipe floor 62us -> 47us; gemm1 is DS-bound
// per R4 model: 78us measured = 80% DS-busy). Same xs/ws staging + dual
// prefetch + 2 barriers/kb as the 78us R2 kernel. Cross-half acc reduction
// through xs at the end (conflict-free layout chunk*512 + lt*4).

__global__ __launch_bounds__(256) void gemm1_kernel(const float* __restrict__ X, const float* __restrict__ W,
      const float* __restrict__ a, float* __restrict__ H,
      float* __restrict__ svec, float* __restrict__ dvec, int n){
  __shared__ float xs[64 * SX];   // 9216 B (also reused for cross-half reduction: 4096 floats)
  __shared__ float ws[32 * 64];   // 8192 B
  int tid = threadIdx.x;
  int r0 = blockIdx.x * 64;
  int h  = tid >> 7;              // k-half: 0 -> kq 0..3, 1 -> kq 4..7
  int lt = tid & 127;
  int rg = lt >> 3;               // 16 row-groups x 4 rows
  int cg = lt & 7;                // 8 col-groups x 8 cols
  int koff = h * 16;              // k offset of this half within the 32-k tile
  int srow = tid >> 3, sc8 = tid & 7;   // staging: 32 rows/pass x 8 float4 chunks

  float4 pfx[2], pfw[2];
  #pragma unroll
  for (int p = 0; p < 2; p++){
    int row = p * 32 + srow;
    int gr = r0 + row;
    pfx[p] = make_float4(0.f, 0.f, 0.f, 0.f);
    if (gr < n) pfx[p] = *(const float4*)(X + (size_t)gr * IN_DIM + sc8 * 4);
  }
  #pragma unroll
  for (int p = 0; p < 2; p++){
    int idx = p * 256 + tid;
    int k = idx >> 4, c4 = idx & 15;
    pfw[p] = *(const float4*)(W + (size_t)k * 64 + c4 * 4);
  }

  float acc[4][8];
  #pragma unroll
  for (int i = 0; i < 4; i++)
    #pragma unroll
    for (int j = 0; j < 8; j++) acc[i][j] = 0.f;

  for (int kb = 0; kb < 8; kb++){
    __syncthreads();
    #pragma unroll
    for (int p = 0; p < 2; p++){
      int row = p * 32 + srow;
      *(float4*)(xs + row * SX + sc8 * 4) = pfx[p];
    }
    #pragma unroll
    for (int p = 0; p < 2; p++){
      int idx = p * 256 + tid;
      int k = idx >> 4, c4 = idx & 15;
      *(float4*)(ws + k * 64 + c4 * 4) = pfw[p];
    }
    if (kb < 7){
      #pragma unroll
      for (int p = 0; p < 2; p++){
        int row = p * 32 + srow;
        int gr = r0 + row;
        pfx[p] = make_float4(0.f, 0.f, 0.f, 0.f);
        if (gr < n) pfx[p] = *(const float4*)(X + (size_t)gr * IN_DIM + (kb + 1) * 32 + sc8 * 4);
      }
      #pragma unroll
      for (int p = 0; p < 2; p++){
        int idx = p * 256 + tid;
        int k = idx >> 4, c4 = idx & 15;
        pfw[p] = *(const float4*)(W + (size_t)((kb + 1) * 32 + k) * 64 + c4 * 4);
      }
    }
    __syncthreads();
    #pragma unroll
    for (int kq0 = 0; kq0 < 4; kq0++){
      int kbase = koff + kq0 * 4;   // wave-uniform k within tile
      float xr[4][4];
      #pragma unroll
      for (int i = 0; i < 4; i++){
        float4 v = *(const float4*)(xs + (rg * 4 + i) * SX + kbase);
        xr[i][0] = v.x; xr[i][1] = v.y; xr[i][2] = v.z; xr[i][3] = v.w;
      }
      #pragma unroll
      for (int dk = 0; dk < 4; dk++){
        float4 wA = *(const float4*)(ws + (size_t)(kbase + dk) * 64 + cg * 8);
        float4 wB = *(const float4*)(ws + (size_t)(kbase + dk) * 64 + cg * 8 + 4);
        #pragma unroll
        for (int i = 0; i < 4; i++){
          acc[i][0] = fmaf(xr[i][dk], wA.x, acc[i][0]);
          acc[i][1] = fmaf(xr[i][dk], wA.y, acc[i][1]);
          acc[i][2] = fmaf(xr[i][dk], wA.z, acc[i][2]);
          acc[i][3] = fmaf(xr[i][dk], wA.w, acc[i][3]);
          acc[i][4] = fmaf(xr[i][dk], wB.x, acc[i][4]);
          acc[i][5] = fmaf(xr[i][dk], wB.y, acc[i][5]);
          acc[i][6] = fmaf(xr[i][dk], wB.z, acc[i][6]);
          acc[i][7] = fmaf(xr[i][dk], wB.w, acc[i][7]);
        }
      }
    }
  }

  // cross-half reduction: half 1 dumps acc into xs (conflict-free: lane-major),
  // half 0 accumulates and runs the epilogue.
  __syncthreads();
  if (h == 1){
    #pragma unroll
    for (int i = 0; i < 4; i++){
      #pragma unroll
      for (int jj = 0; jj < 2; jj++)
        *(float4*)(xs + (i * 2 + jj) * 512 + lt * 4) =
            make_float4(acc[i][jj * 4], acc[i][jj * 4 + 1], acc[i][jj * 4 + 2], acc[i][jj * 4 + 3]);
    }
  }
  __syncthreads();
  if (h == 0){
    #pragma unroll
    for (int i = 0; i < 4; i++){
      #pragma unroll
      for (int jj = 0; jj < 2; jj++){
        float4 v = *(const float4*)(xs + (i * 2 + jj) * 512 + lt * 4);
        acc[i][jj * 4]     += v.x;
        acc[i][jj * 4 + 1] += v.y;
        acc[i][jj * 4 + 2] += v.z;
        acc[i][jj * 4 + 3] += v.w;
      }
    }
    float av[8], bv[8];
    #pragma unroll
    for (int j = 0; j < 8; j++){ av[j] = a[cg * 8 + j]; bv[j] = a[64 + cg * 8 + j]; }
    float sp[4], dp[4];
    #pragma unroll
    for (int i = 0; i < 4; i++){
      float s = 0.f, d = 0.f;
      #pragma unroll
      for (int j = 0; j < 8; j++){ s = fmaf(acc[i][j], av[j], s); d = fmaf(acc[i][j], bv[j], d); }
      sp[i] = s; dp[i] = d;
    }
    #pragma unroll
    for (int off = 1; off < 8; off <<= 1){
      #pragma unroll
      for (int i = 0; i < 4; i++){
        sp[i] += __shfl_xor(sp[i], off, 8);
        dp[i] += __shfl_xor(dp[i], off, 8);
      }
    }
    #pragma unroll
    for (int i = 0; i < 4; i++){
      int r = r0 + rg * 4 + i;
      if (r < n){
        *(float4*)(H + (size_t)r * 64 + cg * 8) =
            make_float4(acc[i][0], acc[i][1], acc[i][2], acc[i][3]);
        *(float4*)(H + (size_t)r * 64 + cg * 8 + 4) =
            make_float4(acc[i][4], acc[i][5], acc[i][6], acc[i][7]);
        if (cg == 0){ svec[r] = sp[i]; dvec[r] = dp[i]; }
      }
    }
  }
}

// ---------------- GEMM 2: hid[N,64] @ W2[64,32] -> H2, s, d ----------------
// BM=64, thread owns 4x2. K=64 staged once, ONE barrier, barrier-free compute.

__global__ __launch_bounds__(256) void gemm2_kernel(const float* __restrict__ X, const float* __restrict__ W,
      const float* __restrict__ a, float* __restrict__ H,
      float* __restrict__ svec, float* __restrict__ dvec, int n){
  __shared__ float xs[64 * SX2];  // 17408 B
  __shared__ float ws[64 * 32];   // 8192 B
  int tid = threadIdx.x;
  int r0 = blockIdx.x * 64;
  int tr = tid >> 4;
  int tc = tid & 15;

  #pragma unroll
  for (int p = 0; p < 4; p++){
    int lin = p * 256 + tid;       // 0..1023
    int row = lin >> 4;            // 0..63
    int c4 = lin & 15;             // 0..15
    int gr = r0 + row;
    float4 v = make_float4(0.f, 0.f, 0.f, 0.f);
    if (gr < n) v = *(const float4*)(X + (size_t)gr * HID + c4 * 4);
    *(float4*)(xs + row * SX2 + c4 * 4) = v;
  }
  #pragma unroll
  for (int p = 0; p < 2; p++){
    int lin = p * 256 + tid;       // 0..511
    int k = lin >> 3, c4 = lin & 7;
    *(float4*)(ws + k * 32 + c4 * 4) = *(const float4*)(W + (size_t)k * 32 + c4 * 4);
  }
  __syncthreads();

  float acc[4][2];
  #pragma unroll
  for (int i = 0; i < 4; i++){ acc[i][0] = 0.f; acc[i][1] = 0.f; }

  #pragma unroll
  for (int kq = 0; kq < 16; kq++){
    float xr[4][4];
    #pragma unroll
    for (int i = 0; i < 4; i++){
      float4 v = *(const float4*)(xs + (tr * 4 + i) * SX2 + kq * 4);
      xr[i][0] = v.x; xr[i][1] = v.y; xr[i][2] = v.z; xr[i][3] = v.w;
    }
    #pragma unroll
    for (int dk = 0; dk < 4; dk++){
      float2 w2 = *(const float2*)(ws + (size_t)(kq * 4 + dk) * 32 + tc * 2);
      #pragma unroll
      for (int i = 0; i < 4; i++){
        acc[i][0] = fmaf(xr[i][dk], w2.x, acc[i][0]);
        acc[i][1] = fmaf(xr[i][dk], w2.y, acc[i][1]);
      }
    }
  }

  float a0 = a[tc * 2], a1 = a[tc * 2 + 1];
  float b0 = a[32 + tc * 2], b1 = a[32 + tc * 2 + 1];
  float sp[4], dp[4];
  #pragma unroll
  for (int i = 0; i < 4; i++){
    sp[i] = fmaf(acc[i][0], a0, acc[i][1] * a1);
    dp[i] = fmaf(acc[i][0], b0, acc[i][1] * b1);
  }
  #pragma unroll
  for (int off = 1; off < 16; off <<= 1){
    #pragma unroll
    for (int i = 0; i < 4; i++){
      sp[i] += __shfl_xor(sp[i], off, 16);
      dp[i] += __shfl_xor(dp[i], off, 16);
    }
  }
  #pragma unroll
  for (int i = 0; i < 4; i++){
    int r = r0 + tr * 4 + i;
    if (r < n){
      *(float2*)(H + (size_t)r * NC + tc * 2) = make_float2(acc[i][0], acc[i][1]);
      if (tc == 0){ svec[r] = sp[i]; dvec[r] = dp[i]; }
    }
  }
}

// ---------------- Aggregate layer 1: chunked two-phase softmax + ELU, D=64, 16 lanes/node ----------------
// PV inner loops: NO break -- invalid edges carry weight exactly 0, dd=0, so all
// 16 gathers issue unconditionally (ILP hides latency). Second 16-block guarded.

__global__ __launch_bounds__(256) void agg1_kernel(const float* __restrict__ H, const float* __restrict__ sv,
      const float* __restrict__ dv, const int* __restrict__ row_ptr, const int* __restrict__ csr,
      float* __restrict__ out, int n){
  int t = blockIdx.x * 256 + threadIdx.x;
  int g = t >> 4, fl = t & 15;
  if (g >= n) return;
  int beg = row_ptr[g], end = row_ptr[g + 1];
  float si = sv[g];
  float m = INF_NEG, l = 0.f;
  float ox = 0.f, oy = 0.f, oz = 0.f, ow = 0.f;

  for (int cb = beg; cb < end; cb += 32){
    int ce = min(cb + 32, end);
    int e0 = cb + fl, e1 = cb + 16 + fl;
    int d0 = 0, d1 = 0;
    float ev0 = INF_NEG, ev1 = INF_NEG;
    if (e0 < ce){ d0 = csr[e0]; ev0 = lrelu(si + dv[d0]); }
    if (e1 < ce){ d1 = csr[e1]; ev1 = lrelu(si + dv[d1]); }
    float lm = fmaxf(ev0, ev1);
    #pragma unroll
    for (int off = 1; off < 16; off <<= 1) lm = fmaxf(lm, __shfl_xor(lm, off, 16));
    float nm = fmaxf(m, lm);
    float alpha = __expf(m - nm);
    m = nm;
    ev0 = __expf(ev0 - nm);   // exactly 0 for invalid edges
    ev1 = __expf(ev1 - nm);
    float ll = ev0 + ev1;
    #pragma unroll
    for (int off = 1; off < 16; off <<= 1) ll += __shfl_xor(ll, off, 16);
    l = l * alpha + ll;
    ox *= alpha; oy *= alpha; oz *= alpha; ow *= alpha;
    #pragma unroll
    for (int jj = 0; jj < 16; jj++){
      float wgt = __shfl(ev0, jj, 16);
      int dd = __shfl(d0, jj, 16);
      float4 v = *(const float4*)(H + (size_t)dd * 64 + fl * 4);
      ox = fmaf(wgt, v.x, ox); oy = fmaf(wgt, v.y, oy);
      oz = fmaf(wgt, v.z, oz); ow = fmaf(wgt, v.w, ow);
    }
    if (ce - cb > 16){
      #pragma unroll
      for (int jj = 0; jj < 16; jj++){
        float wgt = __shfl(ev1, jj, 16);
        int dd = __shfl(d1, jj, 16);
        float4 v = *(const float4*)(H + (size_t)dd * 64 + fl * 4);
        ox = fmaf(wgt, v.x, ox); oy = fmaf(wgt, v.y, oy);
        oz = fmaf(wgt, v.z, oz); ow = fmaf(wgt, v.w, ow);
      }
    }
  }
  float inv = (l > 0.f) ? 1.f / l : 0.f;
  ox *= inv; oy *= inv; oz *= inv; ow *= inv;
  ox = ox > 0.f ? ox : __expf(ox) - 1.f;
  oy = oy > 0.f ? oy : __expf(oy) - 1.f;
  oz = oz > 0.f ? oz : __expf(oz) - 1.f;
  ow = ow > 0.f ? ow : __expf(ow) - 1.f;
  *(float4*)(out + (size_t)g * 64 + fl * 4) = make_float4(ox, oy, oz, ow);
}

// ---------------- Aggregate layer 2: chunked two-phase softmax + log_softmax, D=32, 8 lanes/node ----------------
// Same no-break predicated PV structure; each 8-block guarded.

__global__ __launch_bounds__(256) void agg2_kernel(const float* __restrict__ H, const float* __restrict__ sv,
      const float* __restrict__ dv, const int* __restrict__ row_ptr, const int* __restrict__ csr,
      float* __restrict__ out, int n){
  int t = blockIdx.x * 256 + threadIdx.x;
  int g = t >> 3, fl = t & 7;
  if (g >= n) return;
  int beg = row_ptr[g], end = row_ptr[g + 1];
  float si = sv[g];
  float m = INF_NEG, l = 0.f;
  float ox = 0.f, oy = 0.f, oz = 0.f, ow = 0.f;

  for (int cb = beg; cb < end; cb += 32){
    int ce = min(cb + 32, end);
    float ev[4]; int dd4[4];
    float lm = INF_NEG;
    #pragma unroll
    for (int s = 0; s < 4; s++){
      int e = cb + s * 8 + fl;
      ev[s] = INF_NEG; dd4[s] = 0;
      if (e < ce){ dd4[s] = csr[e]; ev[s] = lrelu(si + dv[dd4[s]]); }
      lm = fmaxf(lm, ev[s]);
    }
    #pragma unroll
    for (int off = 1; off < 8; off <<= 1) lm = fmaxf(lm, __shfl_xor(lm, off, 8));
    float nm = fmaxf(m, lm);
    float alpha = __expf(m - nm);
    m = nm;
    float ll = 0.f;
    #pragma unroll
    for (int s = 0; s < 4; s++){ ev[s] = __expf(ev[s] - nm); ll += ev[s]; }   // 0 for invalid
    #pragma unroll
    for (int off = 1; off < 8; off <<= 1) ll += __shfl_xor(ll, off, 8);
    l = l * alpha + ll;
    ox *= alpha; oy *= alpha; oz *= alpha; ow *= alpha;
    #pragma unroll
    for (int s = 0; s < 4; s++){
      if (ce - cb > s * 8){
        #pragma unroll
        for (int jj = 0; jj < 8; jj++){
          float wgt = __shfl(ev[s], jj, 8);
          int dd = __shfl(dd4[s], jj, 8);
          float4 v = *(const float4*)(H + (size_t)dd * 32 + fl * 4);
          ox = fmaf(wgt, v.x, ox); oy = fmaf(wgt, v.y, oy);
          oz = fmaf(wgt, v.z, oz); ow = fmaf(wgt, v.w, ow);
        }
      }
    }
  }
  float inv = (l > 0.f) ? 1.f / l : 0.f;
  ox *= inv; oy *= inv; oz *= inv; ow *= inv;
  float tm = fmaxf(fmaxf(ox, oy), fmaxf(oz, ow));
  #pragma unroll
  for (int off = 1; off < 8; off <<= 1) tm = fmaxf(tm, __shfl_xor(tm, off, 8));
  float se = __expf(ox - tm) + __expf(oy - tm) + __expf(oz - tm) + __expf(ow - tm);
  #pragma unroll
  for (int off = 1; off < 8; off <<= 1) se += __shfl_xor(se, off, 8);
  float lg = tm + __logf(se);
  *(float4*)(out + (size_t)g * 32 + fl * 4) = make_float4(ox - lg, oy - lg, oz - lg, ow - lg);
}

// ---------------- launch ----------------

extern "C" void kernel_launch(void* const* d_in, const int* in_sizes, int n_in,
                              void* d_out, int out_size, void* d_ws, size_t ws_size,
                              hipStream_t stream) {
  (void)n_in; (void)out_size; (void)ws_size;
  const float* X  = (const float*)d_in[0];
  const int*   EI = (const int*)d_in[1];
  const float* W1 = (const float*)d_in[2];
  const float* W2 = (const float*)d_in[3];
  const float* A1 = (const float*)d_in[4];
  const float* A2 = (const float*)d_in[5];
  float* out = (float*)d_out;

  int N = in_sizes[0] / IN_DIM;
  int E = in_sizes[1] / 2;
  const int* src = EI;
  const int* dst = EI + E;

  auto align_up = [](size_t x){ return (x + 511) & ~(size_t)511; };
  char* w = (char*)d_ws;
  int* counts  = (int*)w;   w += align_up((size_t)N * 4);          // fallback fill only
  int* cursor  = (int*)w;   w += align_up((size_t)MAXNBK * 4);
  int* bbase   = (int*)w;   w += align_up((size_t)MAXNBK * 4);
  int* row_ptr = (int*)w;   w += align_up((size_t)(N + 1) * 4);
  int* bsums   = (int*)w;   w += align_up(1024);
  int* csr     = (int*)w;   w += align_up((size_t)E * 4);
  float* H1    = (float*)w; w += align_up((size_t)N * 64 * 4);
  float* hid   = (float*)w; w += align_up((size_t)N * 64 * 4);
  float* s1    = (float*)w; w += align_up((size_t)N * 4);
  float* d1    = (float*)w; w += align_up((size_t)N * 4);
  float* s2    = (float*)w; w += align_up((size_t)N * 4);
  float* d2    = (float*)w; w += align_up((size_t)N * 4);
  float* H2    = H1;                       // H1 dead after agg1; reuse
  unsigned int* tmp = (unsigned int*)hid;  // hid dead until agg1; nbk*SLOT*4 <= N*64*4

  int nbk = ceil_div(N, 256);

  if (N <= (1 << 17) && nbk <= MAXNBK && (size_t)nbk * SLOT <= (size_t)N * 64){
    hipMemsetAsync(cursor, 0, (size_t)nbk * 4, stream);
    bin_kernel<<<ceil_div(E, BIN_CHUNK), 256, 0, stream>>>(src, dst, cursor, tmp, E, nbk);
    bucket_base_kernel<<<1, 512, 0, stream>>>(cursor, bbase, nbk);
    bucket_scatter_kernel<<<nbk, 256, 0, stream>>>(tmp, cursor, bbase, row_ptr, csr, N);
  } else {
    int nb = ceil_div(N, 1024);
    hipMemsetAsync(counts, 0, (size_t)N * 4, stream);
    hist_kernel<<<ceil_div(E, 256), 256, 0, stream>>>(src, counts, E);
    scan_blocks_kernel<<<nb, 256, 0, stream>>>(counts, row_ptr, bsums, N);
    scan_sums_kernel<<<1, 256, 0, stream>>>(bsums, row_ptr, nb, N, E);
    add_offsets_kernel<<<nb, 1024, 0, stream>>>(row_ptr, bsums, N);
    hipMemsetAsync(counts, 0, (size_t)N * 4, stream);
    scatter_kernel<<<ceil_div(E, 256), 256, 0, stream>>>(src, dst, row_ptr, counts, csr, E);
  }

  gemm1_kernel<<<ceil_div(N, 64), 256, 0, stream>>>(X, W1, A1, H1, s1, d1, N);
  agg1_kernel<<<ceil_div(N * 16, 256), 256, 0, stream>>>(H1, s1, d1, row_ptr, csr, hid, N);
  gemm2_kernel<<<ceil_div(N, 64), 256, 0, stream>>>(hid, W2, A2, H2, s2, d2, N);
  agg2_kernel<<<ceil_div(N * 8, 256), 256, 0, stream>>>(H2, s2, d2, row_ptr, csr, out, N);
}

// Round 8
// 347.664 us; speedup vs baseline: 1.2897x; 1.0105x over previous
//
#include <hip/hip_runtime.h>
#include <hip/hip_fp16.h>
#include <math.h>

#define IN_DIM 256
#define HID 64
#define NC 32
#define NEG 0.01f
#define INF_NEG -1e30f
#define SX 36       // X tile stride (words), BK=32: 16B rows + 4-word pad rotates banks
#define SX2 68      // gemm2 full-K tile stride (words): 64 + 4 pad
#define MAXNBK 512  // max buckets (N <= 131072 for 17-bit dst packing)
#define SLOT 8256   // per-bucket tmp capacity; 33KB stride breaks L2 set aliasing
#define BCAP 12288  // bucket scatter LDS capacity (entries)
#define BIN_CHUNK 4096  // 391 blocks (1.5/CU) + 31KB LDS (5 blocks/CU)

static inline int ceil_div(int a, int b){ return (a + b - 1) / b; }

static __device__ __forceinline__ float lrelu(float x){ return x > 0.f ? x : NEG * x; }

// ---------------- CSR build ----------------

// Phase A: bucket edges by src>>8 into fixed slots tmp[b*SLOT ...], entry = (src&255)<<17 | dst.
// LDS-reorders each chunk bucket-contiguously so global writes are coalesced runs.
__global__ __launch_bounds__(256) void bin_kernel(const int* __restrict__ src,
      const int* __restrict__ dst, int* __restrict__ cursor,
      unsigned int* __restrict__ tmp, int E, int nbk){
  __shared__ unsigned int payload[BIN_CHUNK];
  __shared__ unsigned short bid[BIN_CHUNK];
  __shared__ int cnt[MAXNBK];
  __shared__ int lofs[MAXNBK];
  __shared__ int gbase[MAXNBK];
  __shared__ int s2[256];
  int tid = threadIdx.x;
  int beg = blockIdx.x * BIN_CHUNK;
  int end = min(E, beg + BIN_CHUNK);
  int len = end - beg;

  for (int i = tid; i < MAXNBK; i += 256) cnt[i] = 0;
  __syncthreads();
  for (int e = beg + tid; e < end; e += 256)
    atomicAdd(&cnt[src[e] >> 8], 1);
  __syncthreads();
  // exclusive scan of cnt[0..511] (2 elems/thread)
  int a0 = cnt[2 * tid], a1 = cnt[2 * tid + 1];
  int pair = a0 + a1;
  s2[tid] = pair; __syncthreads();
  int val = pair;
  for (int off = 1; off < 256; off <<= 1){
    int add = (tid >= off) ? s2[tid - off] : 0;
    __syncthreads();
    val += add; s2[tid] = val;
    __syncthreads();
  }
  int ep = val - pair;
  lofs[2 * tid] = ep;
  lofs[2 * tid + 1] = ep + a0;
  __syncthreads();
  // reserve global runs, reset cnt as rank counters
  for (int i = tid; i < nbk; i += 256){
    int c = cnt[i];
    gbase[i] = (c > 0) ? atomicAdd(&cursor[i], c) : 0;
  }
  __syncthreads();
  for (int i = tid; i < MAXNBK; i += 256) cnt[i] = 0;
  __syncthreads();
  // reorder into LDS bucket-contiguously
  for (int e = beg + tid; e < end; e += 256){
    int s = src[e];
    int b = s >> 8;
    int r = atomicAdd(&cnt[b], 1);
    int pos = lofs[b] + r;
    payload[pos] = ((unsigned)(s & 255) << 17) | (unsigned)dst[e];
    bid[pos] = (unsigned short)b;
  }
  __syncthreads();
  // coalesced run writes
  for (int pos = tid; pos < len; pos += 256){
    int b = bid[pos];
    int idx = pos - lofs[b];
    int g = gbase[b] + idx;
    if (g < SLOT) tmp[(size_t)b * SLOT + g] = payload[pos];
  }
}

// Phase B: exclusive scan of bucket counts -> bucket segment bases. One block.
__global__ __launch_bounds__(512) void bucket_base_kernel(const int* __restrict__ cursor,
      int* __restrict__ bbase, int nbk){
  __shared__ int sh[512];
  int tid = threadIdx.x;
  int v = (tid < nbk) ? min(cursor[tid], SLOT) : 0;
  sh[tid] = v; __syncthreads();
  int val = v;
  for (int off = 1; off < 512; off <<= 1){
    int add = (tid >= off) ? sh[tid - off] : 0;
    __syncthreads();
    val += add; sh[tid] = val;
    __syncthreads();
  }
  if (tid < nbk) bbase[tid] = val - v;
}

// Phase C: one block per bucket; derive row_ptr, scatter to exact positions in LDS,
// write csr coalesced.
__global__ __launch_bounds__(256) void bucket_scatter_kernel(const unsigned int* __restrict__ tmp,
      const int* __restrict__ cursor, const int* __restrict__ bbase,
      int* __restrict__ row_ptr, int* __restrict__ csr, int n){
  __shared__ int cnt[256];
  __shared__ int cur[256];
  __shared__ int lbuf[BCAP];
  int tid = threadIdx.x;
  int b = blockIdx.x;
  int n0 = b << 8;
  int nn = min(256, n - n0);
  int len = min(cursor[b], SLOT);
  int segb = bbase[b];
  const unsigned int* T = tmp + (size_t)b * SLOT;
  cnt[tid] = 0;
  __syncthreads();
  for (int e = tid; e < len; e += 256) atomicAdd(&cnt[T[e] >> 17], 1);
  __syncthreads();
  int tv = cnt[tid];
  int val = tv;
  for (int off = 1; off < 256; off <<= 1){
    int add = (tid >= off) ? cnt[tid - off] : 0;
    __syncthreads();
    val += add; cnt[tid] = val;
    __syncthreads();
  }
  int excl = val - tv;
  cur[tid] = excl;
  if (tid < nn) row_ptr[n0 + tid] = segb + excl;
  if (n0 + nn == n && tid == 0) row_ptr[n] = segb + len;
  __syncthreads();
  if (len <= BCAP){
    for (int e = tid; e < len; e += 256){
      unsigned v = T[e];
      int pos = atomicAdd(&cur[v >> 17], 1);
      lbuf[pos] = (int)(v & 0x1FFFF);
    }
    __syncthreads();
    for (int e = tid; e < len; e += 256) csr[segb + e] = lbuf[e];
  } else {
    for (int e = tid; e < len; e += 256){
      unsigned v = T[e];
      int pos = atomicAdd(&cur[v >> 17], 1);
      csr[segb + pos] = (int)(v & 0x1FFFF);
    }
  }
}

// ---- fallback CSR path (N > 2^17 only; never hit at this problem size) ----

__global__ void hist_kernel(const int* __restrict__ src, int* __restrict__ counts, int E){
  int i = blockIdx.x * blockDim.x + threadIdx.x;
  if (i < E) atomicAdd(&counts[src[i]], 1);
}
__global__ void scan_blocks_kernel(const int* __restrict__ counts, int* __restrict__ excl,
                                   int* __restrict__ bsums, int n){
  __shared__ int sh[256];
  int tid = threadIdx.x;
  int base = blockIdx.x * 1024 + tid * 4;
  int c[4]; int tsum = 0;
  #pragma unroll
  for (int j = 0; j < 4; j++){ int i = base + j; c[j] = (i < n) ? counts[i] : 0; tsum += c[j]; }
  sh[tid] = tsum; __syncthreads();
  int val = tsum;
  for (int off = 1; off < 256; off <<= 1){
    int add = (tid >= off) ? sh[tid - off] : 0;
    __syncthreads();
    val += add; sh[tid] = val;
    __syncthreads();
  }
  int p = val - tsum;
  #pragma unroll
  for (int j = 0; j < 4; j++){ int i = base + j; if (i < n) excl[i] = p; p += c[j]; }
  if (tid == 255) bsums[blockIdx.x] = val;
}
__global__ void scan_sums_kernel(int* __restrict__ bsums, int* __restrict__ row_ptr,
                                 int nb, int n, int E){
  __shared__ int sh[256];
  int tid = threadIdx.x;
  int v = (tid < nb) ? bsums[tid] : 0;
  sh[tid] = v; __syncthreads();
  int val = v;
  for (int off = 1; off < 256; off <<= 1){
    int add = (tid >= off) ? sh[tid - off] : 0;
    __syncthreads();
    val += add; sh[tid] = val;
    __syncthreads();
  }
  if (tid < nb) bsums[tid] = val - v;
  if (tid == 0) row_ptr[n] = E;
}
__global__ void add_offsets_kernel(int* __restrict__ excl, const int* __restrict__ bsums, int n){
  int i = blockIdx.x * 1024 + threadIdx.x;
  if (i < n) excl[i] += bsums[blockIdx.x];
}
__global__ void scatter_kernel(const int* __restrict__ src, const int* __restrict__ dst,
                               const int* __restrict__ row_ptr, int* __restrict__ fill,
                               int* __restrict__ csr, int E){
  int i = blockIdx.x * blockDim.x + threadIdx.x;
  if (i >= E) return;
  int s = src[i];
  int pos = row_ptr[s] + atomicAdd(&fill[s], 1);
  csr[pos] = dst[i];
}

// ---------------- GEMM 1: X[N,256] @ W1[256,64] -> H, s, d ----------------
// R2/R5 config (measured 78us, VGPR 44): BM=64, 4x4 tile, BK=32, xs+ws in LDS,
// dual register prefetch, 2 barriers/kb, grid 1563 fully resident. FROZEN --
// 5 structural alternatives (BK=64, W-from-global, W-reg-dbuf, BM=128, k-split)
// all measured slower; this is the structure-local optimum.

__global__ __launch_bounds__(256) void gemm1_kernel(const float* __restrict__ X, const float* __restrict__ W,
      const float* __restrict__ a, float* __restrict__ H,
      float* __restrict__ svec, float* __restrict__ dvec, int n){
  __shared__ float xs[64 * SX];   // 9216 B
  __shared__ float ws[32 * 64];   // 8192 B
  int tid = threadIdx.x;
  int r0 = blockIdx.x * 64;
  int tr = tid >> 4;              // 16 row-groups x 4 rows
  int tc = tid & 15;              // 16 col-groups x 4 cols
  int srow = tid >> 3, sc8 = tid & 7;   // staging: 32 rows/pass x 8 float4 chunks

  float4 pfx[2], pfw[2];
  #pragma unroll
  for (int p = 0; p < 2; p++){
    int row = p * 32 + srow;
    int gr = r0 + row;
    pfx[p] = make_float4(0.f, 0.f, 0.f, 0.f);
    if (gr < n) pfx[p] = *(const float4*)(X + (size_t)gr * IN_DIM + sc8 * 4);
  }
  #pragma unroll
  for (int p = 0; p < 2; p++){
    int idx = p * 256 + tid;
    int k = idx >> 4, c4 = idx & 15;
    pfw[p] = *(const float4*)(W + (size_t)k * 64 + c4 * 4);
  }

  float acc[4][4];
  #pragma unroll
  for (int i = 0; i < 4; i++)
    #pragma unroll
    for (int j = 0; j < 4; j++) acc[i][j] = 0.f;

  for (int kb = 0; kb < 8; kb++){
    __syncthreads();
    #pragma unroll
    for (int p = 0; p < 2; p++){
      int row = p * 32 + srow;
      *(float4*)(xs + row * SX + sc8 * 4) = pfx[p];
    }
    #pragma unroll
    for (int p = 0; p < 2; p++){
      int idx = p * 256 + tid;
      int k = idx >> 4, c4 = idx & 15;
      *(float4*)(ws + k * 64 + c4 * 4) = pfw[p];
    }
    if (kb < 7){
      #pragma unroll
      for (int p = 0; p < 2; p++){
        int row = p * 32 + srow;
        int gr = r0 + row;
        pfx[p] = make_float4(0.f, 0.f, 0.f, 0.f);
        if (gr < n) pfx[p] = *(const float4*)(X + (size_t)gr * IN_DIM + (kb + 1) * 32 + sc8 * 4);
      }
      #pragma unroll
      for (int p = 0; p < 2; p++){
        int idx = p * 256 + tid;
        int k = idx >> 4, c4 = idx & 15;
        pfw[p] = *(const float4*)(W + (size_t)((kb + 1) * 32 + k) * 64 + c4 * 4);
      }
    }
    __syncthreads();
    #pragma unroll
    for (int kq = 0; kq < 8; kq++){
      float xr[4][4];
      #pragma unroll
      for (int i = 0; i < 4; i++){
        float4 v = *(const float4*)(xs + (tr * 4 + i) * SX + kq * 4);
        xr[i][0] = v.x; xr[i][1] = v.y; xr[i][2] = v.z; xr[i][3] = v.w;
      }
      #pragma unroll
      for (int dk = 0; dk < 4; dk++){
        float4 w4 = *(const float4*)(ws + (size_t)(kq * 4 + dk) * 64 + tc * 4);
        float wv[4] = {w4.x, w4.y, w4.z, w4.w};
        #pragma unroll
        for (int i = 0; i < 4; i++)
          #pragma unroll
          for (int j = 0; j < 4; j++) acc[i][j] = fmaf(xr[i][dk], wv[j], acc[i][j]);
      }
    }
  }

  float av[4], bv[4];
  #pragma unroll
  for (int j = 0; j < 4; j++){ av[j] = a[tc * 4 + j]; bv[j] = a[64 + tc * 4 + j]; }
  float sp[4], dp[4];
  #pragma unroll
  for (int i = 0; i < 4; i++){
    float s = 0.f, d = 0.f;
    #pragma unroll
    for (int j = 0; j < 4; j++){ s = fmaf(acc[i][j], av[j], s); d = fmaf(acc[i][j], bv[j], d); }
    sp[i] = s; dp[i] = d;
  }
  #pragma unroll
  for (int off = 1; off < 16; off <<= 1){
    #pragma unroll
    for (int i = 0; i < 4; i++){
      sp[i] += __shfl_xor(sp[i], off, 16);
      dp[i] += __shfl_xor(dp[i], off, 16);
    }
  }
  #pragma unroll
  for (int i = 0; i < 4; i++){
    int r = r0 + tr * 4 + i;
    if (r < n){
      *(float4*)(H + (size_t)r * 64 + tc * 4) = make_float4(acc[i][0], acc[i][1], acc[i][2], acc[i][3]);
      if (tc == 0){ svec[r] = sp[i]; dvec[r] = dp[i]; }
    }
  }
}

// ---------------- GEMM 2: hid[N,64] @ W2[64,32] -> H2 (fp16), s, d ----------------
// BM=64, thread owns 4x2. K=64 staged once, ONE barrier, barrier-free compute.
// H2 stored as __half: s2/d2 come from the fp32 accumulator (logits stay clean);
// only the value-averaging path in agg2 sees fp16 (err ~0.02, safe). Halves
// agg2's gather traffic (205 -> 102 MB) and the H2 write.

__global__ __launch_bounds__(256) void gemm2_kernel(const float* __restrict__ X, const float* __restrict__ W,
      const float* __restrict__ a, __half* __restrict__ H,
      float* __restrict__ svec, float* __restrict__ dvec, int n){
  __shared__ float xs[64 * SX2];  // 17408 B
  __shared__ float ws[64 * 32];   // 8192 B
  int tid = threadIdx.x;
  int r0 = blockIdx.x * 64;
  int tr = tid >> 4;
  int tc = tid & 15;

  #pragma unroll
  for (int p = 0; p < 4; p++){
    int lin = p * 256 + tid;       // 0..1023
    int row = lin >> 4;            // 0..63
    int c4 = lin & 15;             // 0..15
    int gr = r0 + row;
    float4 v = make_float4(0.f, 0.f, 0.f, 0.f);
    if (gr < n) v = *(const float4*)(X + (size_t)gr * HID + c4 * 4);
    *(float4*)(xs + row * SX2 + c4 * 4) = v;
  }
  #pragma unroll
  for (int p = 0; p < 2; p++){
    int lin = p * 256 + tid;       // 0..511
    int k = lin >> 3, c4 = lin & 7;
    *(float4*)(ws + k * 32 + c4 * 4) = *(const float4*)(W + (size_t)k * 32 + c4 * 4);
  }
  __syncthreads();

  float acc[4][2];
  #pragma unroll
  for (int i = 0; i < 4; i++){ acc[i][0] = 0.f; acc[i][1] = 0.f; }

  #pragma unroll
  for (int kq = 0; kq < 16; kq++){
    float xr[4][4];
    #pragma unroll
    for (int i = 0; i < 4; i++){
      float4 v = *(const float4*)(xs + (tr * 4 + i) * SX2 + kq * 4);
      xr[i][0] = v.x; xr[i][1] = v.y; xr[i][2] = v.z; xr[i][3] = v.w;
    }
    #pragma unroll
    for (int dk = 0; dk < 4; dk++){
      float2 w2 = *(const float2*)(ws + (size_t)(kq * 4 + dk) * 32 + tc * 2);
      #pragma unroll
      for (int i = 0; i < 4; i++){
        acc[i][0] = fmaf(xr[i][dk], w2.x, acc[i][0]);
        acc[i][1] = fmaf(xr[i][dk], w2.y, acc[i][1]);
      }
    }
  }

  float a0 = a[tc * 2], a1 = a[tc * 2 + 1];
  float b0 = a[32 + tc * 2], b1 = a[32 + tc * 2 + 1];
  float sp[4], dp[4];
  #pragma unroll
  for (int i = 0; i < 4; i++){
    sp[i] = fmaf(acc[i][0], a0, acc[i][1] * a1);
    dp[i] = fmaf(acc[i][0], b0, acc[i][1] * b1);
  }
  #pragma unroll
  for (int off = 1; off < 16; off <<= 1){
    #pragma unroll
    for (int i = 0; i < 4; i++){
      sp[i] += __shfl_xor(sp[i], off, 16);
      dp[i] += __shfl_xor(dp[i], off, 16);
    }
  }
  #pragma unroll
  for (int i = 0; i < 4; i++){
    int r = r0 + tr * 4 + i;
    if (r < n){
      __half2 h01 = __floats2half2_rn(acc[i][0], acc[i][1]);
      *(__half2*)(H + (size_t)r * NC + tc * 2) = h01;
      if (tc == 0){ svec[r] = sp[i]; dvec[r] = dp[i]; }
    }
  }
}

// ---------------- Aggregate layer 1: chunked two-phase softmax + ELU, D=64, 16 lanes/node ----------------
// PV inner loops: NO break -- invalid edges carry weight exactly 0, dd=0, so all
// 16 gathers issue unconditionally (ILP hides latency). Second 16-block guarded.
// H1 stays fp32: fp16 here would perturb layer-2 logits (s2=hid*(W2 a2), x60
// amplification -> ~0.3 logit error -> attention-weight flips at soft-competition
// nodes -> output errors >> 1). Verified-unsafe; do not quantize this path.

__global__ __launch_bounds__(256) void agg1_kernel(const float* __restrict__ H, const float* __restrict__ sv,
      const float* __restrict__ dv, const int* __restrict__ row_ptr, const int* __restrict__ csr,
      float* __restrict__ out, int n){
  int t = blockIdx.x * 256 + threadIdx.x;
  int g = t >> 4, fl = t & 15;
  if (g >= n) return;
  int beg = row_ptr[g], end = row_ptr[g + 1];
  float si = sv[g];
  float m = INF_NEG, l = 0.f;
  float ox = 0.f, oy = 0.f, oz = 0.f, ow = 0.f;

  for (int cb = beg; cb < end; cb += 32){
    int ce = min(cb + 32, end);
    int e0 = cb + fl, e1 = cb + 16 + fl;
    int d0 = 0, d1 = 0;
    float ev0 = INF_NEG, ev1 = INF_NEG;
    if (e0 < ce){ d0 = csr[e0]; ev0 = lrelu(si + dv[d0]); }
    if (e1 < ce){ d1 = csr[e1]; ev1 = lrelu(si + dv[d1]); }
    float lm = fmaxf(ev0, ev1);
    #pragma unroll
    for (int off = 1; off < 16; off <<= 1) lm = fmaxf(lm, __shfl_xor(lm, off, 16));
    float nm = fmaxf(m, lm);
    float alpha = __expf(m - nm);
    m = nm;
    ev0 = __expf(ev0 - nm);   // exactly 0 for invalid edges
    ev1 = __expf(ev1 - nm);
    float ll = ev0 + ev1;
    #pragma unroll
    for (int off = 1; off < 16; off <<= 1) ll += __shfl_xor(ll, off, 16);
    l = l * alpha + ll;
    ox *= alpha; oy *= alpha; oz *= alpha; ow *= alpha;
    #pragma unroll
    for (int jj = 0; jj < 16; jj++){
      float wgt = __shfl(ev0, jj, 16);
      int dd = __shfl(d0, jj, 16);
      float4 v = *(const float4*)(H + (size_t)dd * 64 + fl * 4);
      ox = fmaf(wgt, v.x, ox); oy = fmaf(wgt, v.y, oy);
      oz = fmaf(wgt, v.z, oz); ow = fmaf(wgt, v.w, ow);
    }
    if (ce - cb > 16){
      #pragma unroll
      for (int jj = 0; jj < 16; jj++){
        float wgt = __shfl(ev1, jj, 16);
        int dd = __shfl(d1, jj, 16);
        float4 v = *(const float4*)(H + (size_t)dd * 64 + fl * 4);
        ox = fmaf(wgt, v.x, ox); oy = fmaf(wgt, v.y, oy);
        oz = fmaf(wgt, v.z, oz); ow = fmaf(wgt, v.w, ow);
      }
    }
  }
  float inv = (l > 0.f) ? 1.f / l : 0.f;
  ox *= inv; oy *= inv; oz *= inv; ow *= inv;
  ox = ox > 0.f ? ox : __expf(ox) - 1.f;
  oy = oy > 0.f ? oy : __expf(oy) - 1.f;
  oz = oz > 0.f ? oz : __expf(oz) - 1.f;
  ow = ow > 0.f ? ow : __expf(ow) - 1.f;
  *(float4*)(out + (size_t)g * 64 + fl * 4) = make_float4(ox, oy, oz, ow);
}

// ---------------- Aggregate layer 2: chunked two-phase softmax + log_softmax, D=32, 8 lanes/node ----------------
// Same no-break predicated PV structure; each 8-block guarded. H2 gathered as
// fp16 (8B/lane uint2, converted to fp32 for accumulation) -- halves gather bytes.

__global__ __launch_bounds__(256) void agg2_kernel(const __half* __restrict__ H, const float* __restrict__ sv,
      const float* __restrict__ dv, const int* __restrict__ row_ptr, const int* __restrict__ csr,
      float* __restrict__ out, int n){
  int t = blockIdx.x * 256 + threadIdx.x;
  int g = t >> 3, fl = t & 7;
  if (g >= n) return;
  int beg = row_ptr[g], end = row_ptr[g + 1];
  float si = sv[g];
  float m = INF_NEG, l = 0.f;
  float ox = 0.f, oy = 0.f, oz = 0.f, ow = 0.f;

  for (int cb = beg; cb < end; cb += 32){
    int ce = min(cb + 32, end);
    float ev[4]; int dd4[4];
    float lm = INF_NEG;
    #pragma unroll
    for (int s = 0; s < 4; s++){
      int e = cb + s * 8 + fl;
      ev[s] = INF_NEG; dd4[s] = 0;
      if (e < ce){ dd4[s] = csr[e]; ev[s] = lrelu(si + dv[dd4[s]]); }
      lm = fmaxf(lm, ev[s]);
    }
    #pragma unroll
    for (int off = 1; off < 8; off <<= 1) lm = fmaxf(lm, __shfl_xor(lm, off, 8));
    float nm = fmaxf(m, lm);
    float alpha = __expf(m - nm);
    m = nm;
    float ll = 0.f;
    #pragma unroll
    for (int s = 0; s < 4; s++){ ev[s] = __expf(ev[s] - nm); ll += ev[s]; }   // 0 for invalid
    #pragma unroll
    for (int off = 1; off < 8; off <<= 1) ll += __shfl_xor(ll, off, 8);
    l = l * alpha + ll;
    ox *= alpha; oy *= alpha; oz *= alpha; ow *= alpha;
    #pragma unroll
    for (int s = 0; s < 4; s++){
      if (ce - cb > s * 8){
        #pragma unroll
        for (int jj = 0; jj < 8; jj++){
          float wgt = __shfl(ev[s], jj, 8);
          int dd = __shfl(dd4[s], jj, 8);
          uint2 raw = *(const uint2*)(H + (size_t)dd * NC + fl * 4);   // 8B: 4 halves
          __half2 h01 = *(__half2*)(&raw.x);
          __half2 h23 = *(__half2*)(&raw.y);
          float2 f01 = __half22float2(h01);
          float2 f23 = __half22float2(h23);
          ox = fmaf(wgt, f01.x, ox); oy = fmaf(wgt, f01.y, oy);
          oz = fmaf(wgt, f23.x, oz); ow = fmaf(wgt, f23.y, ow);
        }
      }
    }
  }
  float inv = (l > 0.f) ? 1.f / l : 0.f;
  ox *= inv; oy *= inv; oz *= inv; ow *= inv;
  float tm = fmaxf(fmaxf(ox, oy), fmaxf(oz, ow));
  #pragma unroll
  for (int off = 1; off < 8; off <<= 1) tm = fmaxf(tm, __shfl_xor(tm, off, 8));
  float se = __expf(ox - tm) + __expf(oy - tm) + __expf(oz - tm) + __expf(ow - tm);
  #pragma unroll
  for (int off = 1; off < 8; off <<= 1) se += __shfl_xor(se, off, 8);
  float lg = tm + __logf(se);
  *(float4*)(out + (size_t)g * 32 + fl * 4) = make_float4(ox - lg, oy - lg, oz - lg, ow - lg);
}

// ---------------- launch ----------------

extern "C" void kernel_launch(void* const* d_in, const int* in_sizes, int n_in,
                              void* d_out, int out_size, void* d_ws, size_t ws_size,
                              hipStream_t stream) {
  (void)n_in; (void)out_size; (void)ws_size;
  const float* X  = (const float*)d_in[0];
  const int*   EI = (const int*)d_in[1];
  const float* W1 = (const float*)d_in[2];
  const float* W2 = (const float*)d_in[3];
  const float* A1 = (const float*)d_in[4];
  const float* A2 = (const float*)d_in[5];
  float* out = (float*)d_out;

  int N = in_sizes[0] / IN_DIM;
  int E = in_sizes[1] / 2;
  const int* src = EI;
  const int* dst = EI + E;

  auto align_up = [](size_t x){ return (x + 511) & ~(size_t)511; };
  char* w = (char*)d_ws;
  int* counts  = (int*)w;   w += align_up((size_t)N * 4);          // fallback fill only
  int* cursor  = (int*)w;   w += align_up((size_t)MAXNBK * 4);
  int* bbase   = (int*)w;   w += align_up((size_t)MAXNBK * 4);
  int* row_ptr = (int*)w;   w += align_up((size_t)(N + 1) * 4);
  int* bsums   = (int*)w;   w += align_up(1024);
  int* csr     = (int*)w;   w += align_up((size_t)E * 4);
  float* H1    = (float*)w; w += align_up((size_t)N * 64 * 4);
  float* hid   = (float*)w; w += align_up((size_t)N * 64 * 4);
  float* s1    = (float*)w; w += align_up((size_t)N * 4);
  float* d1    = (float*)w; w += align_up((size_t)N * 4);
  float* s2    = (float*)w; w += align_up((size_t)N * 4);
  float* d2    = (float*)w; w += align_up((size_t)N * 4);
  __half* H2h  = (__half*)H1;              // H1 dead after agg1; reuse as fp16 H2
  unsigned int* tmp = (unsigned int*)hid;  // hid dead until agg1; nbk*SLOT*4 <= N*64*4

  int nbk = ceil_div(N, 256);

  if (N <= (1 << 17) && nbk <= MAXNBK && (size_t)nbk * SLOT <= (size_t)N * 64){
    hipMemsetAsync(cursor, 0, (size_t)nbk * 4, stream);
    bin_kernel<<<ceil_div(E, BIN_CHUNK), 256, 0, stream>>>(src, dst, cursor, tmp, E, nbk);
    bucket_base_kernel<<<1, 512, 0, stream>>>(cursor, bbase, nbk);
    bucket_scatter_kernel<<<nbk, 256, 0, stream>>>(tmp, cursor, bbase, row_ptr, csr, N);
  } else {
    int nb = ceil_div(N, 1024);
    hipMemsetAsync(counts, 0, (size_t)N * 4, stream);
    hist_kernel<<<ceil_div(E, 256), 256, 0, stream>>>(src, counts, E);
    scan_blocks_kernel<<<nb, 256, 0, stream>>>(counts, row_ptr, bsums, N);
    scan_sums_kernel<<<1, 256, 0, stream>>>(bsums, row_ptr, nb, N, E);
    add_offsets_kernel<<<nb, 1024, 0, stream>>>(row_ptr, bsums, N);
    hipMemsetAsync(counts, 0, (size_t)N * 4, stream);
    scatter_kernel<<<ceil_div(E, 256), 256, 0, stream>>>(src, dst, row_ptr, counts, csr, E);
  }

  gemm1_kernel<<<ceil_div(N, 64), 256, 0, stream>>>(X, W1, A1, H1, s1, d1, N);
  agg1_kernel<<<ceil_div(N * 16, 256), 256, 0, stream>>>(H1, s1, d1, row_ptr, csr, hid, N);
  gemm2_kernel<<<ceil_div(N, 64), 256, 0, stream>>>(hid, W2, A2, H2h, s2, d2, N);
  agg2_kernel<<<ceil_div(N * 8, 256), 256, 0, stream>>>(H2h, s2, d2, row_ptr, csr, out, N);
}